// Round 4
// baseline (2129.580 us; speedup 1.0000x reference)
//
#include <hip/hip_runtime.h>
#include <hip/hip_bf16.h>

typedef __hip_bfloat16 bf16;
static __device__ __forceinline__ float b2f(bf16 v){ return __bfloat162float(v); }
static __device__ __forceinline__ bf16  f2b(float v){ return __float2bfloat16(v); }

#define SCALE_T 0.17677669529663687f   // 32^-0.5

// ---------------------------------------------------------------------------
// LDS-tiled fp32 GEMM: out = (A[M,K] @ W[K,N] + bias) * scale
// a_mode: 0 = A f32 [M,K];  1 = A bf16 [M,K] (workspace intermediate);
//         2 = A = concat(A f32[M,256], Xd f32[M,64], Xs f32[M,64]) (K=384)
// W/bias are f32 (external inputs); writes outF (f32) and/or outB (bf16).
// M%64==0, N%64==0, K%16==0 at all call sites.
// ---------------------------------------------------------------------------
__global__ __launch_bounds__(256) void gemm_kernel(
    const void* __restrict__ A, int a_mode,
    const float* __restrict__ Xd, const float* __restrict__ Xs,
    const float* __restrict__ W, const float* __restrict__ bias,
    float* __restrict__ outF, bf16* __restrict__ outB,
    int M, int K, int N, float scale)
{
    __shared__ float As[16][65];   // [k][m]
    __shared__ float Bs[16][65];   // [k][n]
    const int tid = threadIdx.x;
    const int tx = tid & 15, ty = tid >> 4;
    const int rowBase = blockIdx.y * 64, colBase = blockIdx.x * 64;
    const bf16*  Ab = (const bf16*)A;
    const float* Af = (const float*)A;
    float acc[4][4] = {{0.f}};

    for (int kt = 0; kt < K; kt += 16) {
        for (int l = tid; l < 1024; l += 256) {
            int m = l >> 4, k = l & 15;
            size_t r_ = (size_t)(rowBase + m);
            int kcol = kt + k;
            float av;
            if (a_mode == 2) {
                if (kcol < 256)      av = Af[r_ * 256 + kcol];
                else if (kcol < 320) av = Xd[r_ * 64 + (kcol - 256)];
                else                 av = Xs[r_ * 64 + (kcol - 320)];
            } else if (a_mode == 1) {
                av = b2f(Ab[r_ * K + kcol]);
            } else {
                av = Af[r_ * K + kcol];
            }
            As[k][m] = av;
        }
        for (int l = tid; l < 1024; l += 256) {
            int k = l >> 6, n2 = l & 63;
            Bs[k][n2] = W[(size_t)(kt + k) * N + colBase + n2];
        }
        __syncthreads();
        #pragma unroll
        for (int kk = 0; kk < 16; ++kk) {
            float a0 = As[kk][ty*4+0], a1 = As[kk][ty*4+1];
            float a2 = As[kk][ty*4+2], a3 = As[kk][ty*4+3];
            float b0 = Bs[kk][tx*4+0], b1 = Bs[kk][tx*4+1];
            float b2_ = Bs[kk][tx*4+2], b3 = Bs[kk][tx*4+3];
            acc[0][0] += a0*b0; acc[0][1] += a0*b1; acc[0][2] += a0*b2_; acc[0][3] += a0*b3;
            acc[1][0] += a1*b0; acc[1][1] += a1*b1; acc[1][2] += a1*b2_; acc[1][3] += a1*b3;
            acc[2][0] += a2*b0; acc[2][1] += a2*b1; acc[2][2] += a2*b2_; acc[2][3] += a2*b3;
            acc[3][0] += a3*b0; acc[3][1] += a3*b1; acc[3][2] += a3*b2_; acc[3][3] += a3*b3;
        }
        __syncthreads();
    }
    #pragma unroll
    for (int i = 0; i < 4; ++i)
        #pragma unroll
        for (int j = 0; j < 4; ++j) {
            int row = rowBase + ty*4 + i, col = colBase + tx*4 + j;
            float v = (acc[i][j] + bias[col]) * scale;
            if (outF) outF[(size_t)row * N + col] = v;
            if (outB) outB[(size_t)row * N + col] = f2b(v);
        }
}

// ---------------------------------------------------------------------------
// ref_q_t[r,h,f,d] = mu[c] + exp(ls[c]) * ref_qk[r*32+f, c];  ref_v_t from +256
// (c = h*32+d).  65536 threads.
// ---------------------------------------------------------------------------
__global__ __launch_bounds__(256) void refprep_kernel(
    const float* __restrict__ ref_qk, const float* __restrict__ mu,
    const float* __restrict__ ls, float* __restrict__ ref_q_t,
    float* __restrict__ ref_v_t)
{
    int idx = blockIdx.x * 256 + threadIdx.x;          // [r,h,f,d]
    int d = idx & 31, f = (idx >> 5) & 31, h = (idx >> 10) & 7, r = idx >> 13;
    int c = h * 32 + d;
    size_t src = (size_t)(r * 32 + f) * 512 + c;
    ref_q_t[idx] = mu[c] + __expf(ls[c]) * ref_qk[src];
    ref_v_t[idx] = ref_qk[src + 256];
}

// ---------------------------------------------------------------------------
// ref_attn[r,h,w,n,f] = sum_d (q[b,h,n,d]*SCALE) * ref_q_t[r,h,f,d]
// grid = 4096 blocks of 256.
// ---------------------------------------------------------------------------
__global__ __launch_bounds__(256) void refattn_kernel(
    const bf16* __restrict__ qkv, const float* __restrict__ ref_q_t,
    bf16* __restrict__ ref_attn)
{
    int blk = blockIdx.x;
    int w = blk & 63, h = (blk >> 6) & 7, r = blk >> 9;
    int b = r * 64 + w;
    __shared__ float qt[49 * 32];     // [n][d]
    __shared__ float rq[32 * 33];     // [f][d], padded
    int tid = threadIdx.x;
    for (int l = tid; l < 1568; l += 256) {
        int n = l >> 5, d = l & 31;
        qt[l] = b2f(qkv[(size_t)(b * 49 + n) * 768 + h * 32 + d]) * SCALE_T;
    }
    for (int l = tid; l < 1024; l += 256) {
        int f = l >> 5, d = l & 31;
        rq[f * 33 + d] = ref_q_t[(size_t)((r * 8 + h) * 32 + f) * 32 + d];
    }
    __syncthreads();
    for (int l = tid; l < 1568; l += 256) {
        int n = l >> 5, f = l & 31;
        float acc = 0.f;
        #pragma unroll
        for (int d2 = 0; d2 < 32; ++d2) acc += qt[n * 32 + d2] * rq[f * 33 + d2];
        ref_attn[(size_t)(((r * 8 + h) * 64 + w) * 49 + n) * 32 + f] = f2b(acc);
    }
}

// ---------------------------------------------------------------------------
// 3x3 SAME conv over [RB=8, 8ch, 3136, 32].  grid = 25088 blocks of 256.
// ---------------------------------------------------------------------------
__global__ __launch_bounds__(256) void conv_kernel(
    const bf16* __restrict__ in, const float* __restrict__ conv_w,
    const float* __restrict__ conv_b, bf16* __restrict__ u)
{
    __shared__ float w_s[576];
    __shared__ float b_s[8];
    int tid = threadIdx.x;
    for (int l = tid; l < 576; l += 256) w_s[l] = conv_w[l];
    if (tid < 8) b_s[tid] = conv_b[tid];
    __syncthreads();
    int idx = blockIdx.x * 256 + tid;          // < 6,422,528
    int f = idx & 31;
    int p = (idx >> 5) % 3136;
    int o = ((idx >> 5) / 3136) & 7;
    int r = idx / (32 * 3136 * 8);
    float acc = b_s[o];
    for (int i = 0; i < 8; ++i) {
        const bf16* ip = in + (size_t)(r * 8 + i) * 3136 * 32;
        #pragma unroll
        for (int ky = 0; ky < 3; ++ky) {
            int pp = p + ky - 1;
            if ((unsigned)pp >= 3136u) continue;
            #pragma unroll
            for (int kx = 0; kx < 3; ++kx) {
                int ff = f + kx - 1;
                if ((unsigned)ff >= 32u) continue;
                acc += b2f(ip[pp * 32 + ff]) * w_s[((o * 8 + i) * 3 + ky) * 3 + kx];
            }
        }
    }
    u[idx] = f2b(acc);
}

// ---------------------------------------------------------------------------
// Per-(r,ch) mean/rstd over contiguous 100352-elem map.  64 blocks.
// ---------------------------------------------------------------------------
__global__ __launch_bounds__(256) void lnstats_kernel(
    const bf16* __restrict__ u, float* __restrict__ stats)
{
    int g = blockIdx.x;
    const bf16* p = u + (size_t)g * 100352;
    int tid = threadIdx.x;
    float s = 0.f, s2 = 0.f;
    for (int i = tid; i < 100352; i += 256) { float v = b2f(p[i]); s += v; s2 += v * v; }
    __shared__ float r1[256], r2[256];
    r1[tid] = s; r2[tid] = s2; __syncthreads();
    for (int st = 128; st > 0; st >>= 1) {
        if (tid < st) { r1[tid] += r1[tid + st]; r2[tid] += r2[tid + st]; }
        __syncthreads();
    }
    if (tid == 0) {
        float mean = r1[0] * (1.f / 100352.f);
        float var  = r2[0] * (1.f / 100352.f) - mean * mean;
        var = fmaxf(var, 0.f);
        stats[g * 2] = mean;
        stats[g * 2 + 1] = rsqrtf(var + 1e-5f);
    }
}

// ref_attn += gelu_exact( (u - mean) * rstd );  grid = 25088 blocks.
__global__ __launch_bounds__(256) void lngelu_kernel(
    const bf16* __restrict__ u, const float* __restrict__ stats,
    bf16* __restrict__ ref_attn)
{
    int idx = blockIdx.x * 256 + threadIdx.x;
    int g = idx / 100352;
    float v = (b2f(u[idx]) - stats[g * 2]) * stats[g * 2 + 1];
    float ge = 0.5f * v * (1.f + erff(v * 0.7071067811865476f));
    ref_attn[idx] = f2b(b2f(ref_attn[idx]) + ge);
}

// ---------------------------------------------------------------------------
// Per (b,n): softmax(32) @ ref_v + q_sc, LN(256)*w+b, @q_proj_w + b + q_sc, *SCALE
// grid = 25088 blocks of 256 (tid = c = h*32+d).
// ---------------------------------------------------------------------------
__global__ __launch_bounds__(256) void qnew_kernel(
    const bf16* __restrict__ qkv, const bf16* __restrict__ ref_attn,
    const float* __restrict__ ref_v_t,
    const float* __restrict__ qnw, const float* __restrict__ qnb,
    const float* __restrict__ qpw, const float* __restrict__ qpb,
    bf16* __restrict__ q_new)
{
    int row = blockIdx.x;               // b*49+n
    int b = row / 49, n = row % 49;
    int r = b >> 6, w = b & 63;
    int tid = threadIdx.x, h = tid >> 5, d = tid & 31;
    __shared__ float s_logit[256], s_p[256], s_red[256], s_t[256];
    __shared__ float s_mean, s_rstd;

    s_logit[tid] = b2f(ref_attn[(size_t)(((r * 8 + h) * 64 + w) * 49 + n) * 32 + d]);
    __syncthreads();
    int base = h * 32;
    float mx = -1e30f;
    #pragma unroll
    for (int f = 0; f < 32; ++f) mx = fmaxf(mx, s_logit[base + f]);
    float sm = 0.f;
    #pragma unroll
    for (int f = 0; f < 32; ++f) sm += __expf(s_logit[base + f] - mx);
    s_p[tid] = __expf(s_logit[base + d] - mx) / sm;
    __syncthreads();

    float y = 0.f;
    const float* rv = ref_v_t + (size_t)((r * 8 + h) * 32) * 32 + d;
    #pragma unroll
    for (int f = 0; f < 32; ++f) y += s_p[base + f] * rv[f * 32];

    float qsc = b2f(qkv[(size_t)row * 768 + tid]);
    float z = y + qsc;

    s_red[tid] = z; __syncthreads();
    for (int st = 128; st > 0; st >>= 1) {
        if (tid < st) s_red[tid] += s_red[tid + st];
        __syncthreads();
    }
    if (tid == 0) s_mean = s_red[0] * (1.f / 256.f);
    __syncthreads();
    float zc = z - s_mean;
    s_red[tid] = zc * zc; __syncthreads();
    for (int st = 128; st > 0; st >>= 1) {
        if (tid < st) s_red[tid] += s_red[tid + st];
        __syncthreads();
    }
    if (tid == 0) s_rstd = rsqrtf(s_red[0] * (1.f / 256.f) + 1e-5f);
    __syncthreads();

    s_t[tid] = zc * s_rstd * qnw[tid] + qnb[tid];
    __syncthreads();
    float o = 0.f;
    for (int k2 = 0; k2 < 256; ++k2) o += s_t[k2] * qpw[k2 * 256 + tid];
    q_new[(size_t)row * 256 + tid] = f2b((o + qpb[tid] + qsc) * SCALE_T);
}

// ---------------------------------------------------------------------------
// Window attention per (b,h): softmax(q_new k^T + bias) @ v.  4096 blocks.
// ---------------------------------------------------------------------------
__global__ __launch_bounds__(256) void winattn_kernel(
    const bf16* __restrict__ qkv, const bf16* __restrict__ q_new,
    const float* __restrict__ rel_bias, bf16* __restrict__ attn_out)
{
    int bh = blockIdx.x;
    int b = bh >> 3, h = bh & 7;
    int tid = threadIdx.x;
    __shared__ float qn[1568], kk[1568], vv[1568], sc[49 * 50];
    for (int l = tid; l < 1568; l += 256) {
        int n = l >> 5, d = l & 31;
        size_t rq = (size_t)(b * 49 + n);
        qn[l] = b2f(q_new[rq * 256 + h * 32 + d]);
        kk[l] = b2f(qkv[rq * 768 + 256 + h * 32 + d]);
        vv[l] = b2f(qkv[rq * 768 + 512 + h * 32 + d]);
    }
    __syncthreads();
    for (int l = tid; l < 2401; l += 256) {
        int n = l / 49, m = l % 49;
        float acc = 0.f;
        #pragma unroll
        for (int d2 = 0; d2 < 32; ++d2) acc += qn[n * 32 + d2] * kk[m * 32 + d2];
        int ni = n / 7, nj = n % 7, mi = m / 7, mj = m % 7;
        int bidx = ((ni - mi + 6) * 13 + (nj - mj + 6)) * 8 + h;
        sc[n * 50 + m] = acc + rel_bias[bidx];
    }
    __syncthreads();
    if (tid < 49) {
        float mx = -1e30f;
        for (int m = 0; m < 49; ++m) mx = fmaxf(mx, sc[tid * 50 + m]);
        float s = 0.f;
        for (int m = 0; m < 49; ++m) { float e = __expf(sc[tid * 50 + m] - mx); sc[tid * 50 + m] = e; s += e; }
        float inv = 1.f / s;
        for (int m = 0; m < 49; ++m) sc[tid * 50 + m] *= inv;
    }
    __syncthreads();
    for (int l = tid; l < 1568; l += 256) {
        int n = l >> 5, d = l & 31;
        float acc = 0.f;
        for (int m = 0; m < 49; ++m) acc += sc[n * 50 + m] * vv[m * 32 + d];
        attn_out[(size_t)(b * 49 + n) * 256 + h * 32 + d] = f2b(acc);
    }
}

// ---------------------------------------------------------------------------
// Class-token attention per (b,h): both depth & seg.  4096 blocks.
// ---------------------------------------------------------------------------
__global__ __launch_bounds__(256) void clsattn_kernel(
    const bf16* __restrict__ t_k, const bf16* __restrict__ t_v,
    const bf16* __restrict__ depth_q, const bf16* __restrict__ seg_q,
    bf16* __restrict__ d_pre, bf16* __restrict__ s_pre)
{
    int bh = blockIdx.x;
    int b = bh >> 3, h = bh & 7;
    int tid = threadIdx.x;
    __shared__ float tk[2352], tv[2352], dq[392], sq[392], pl[2][384];
    for (int l = tid; l < 2352; l += 256) {
        int n = l / 48, t = l % 48;
        size_t row = (size_t)(b * 49 + n);
        tk[l] = b2f(t_k[row * 384 + h * 48 + t]);
        tv[l] = b2f(t_v[row * 384 + h * 48 + t]);
    }
    for (int l = tid; l < 392; l += 256) {
        int n = l / 8, c = l % 8;
        size_t row = (size_t)(b * 49 + n);
        dq[l] = b2f(depth_q[row * 64 + h * 8 + c]);
        sq[l] = b2f(seg_q[row * 64 + h * 8 + c]);
    }
    __syncthreads();
    for (int l = tid; l < 768; l += 256) {
        int which = l / 384, cc = (l % 384) / 48, t = l % 48;
        const float* q = which ? sq : dq;
        float acc = 0.f;
        for (int n = 0; n < 49; ++n) acc += q[n * 8 + cc] * tk[n * 48 + t];
        pl[which][cc * 48 + t] = acc;
    }
    __syncthreads();
    if (tid < 16) {
        int which = tid >> 3, cc = tid & 7;
        float* p = &pl[which][cc * 48];
        float mx = -1e30f;
        for (int t = 0; t < 48; ++t) mx = fmaxf(mx, p[t]);
        float s = 0.f;
        for (int t = 0; t < 48; ++t) { float e = __expf(p[t] - mx); p[t] = e; s += e; }
        float inv = 1.f / s;
        for (int t = 0; t < 48; ++t) p[t] *= inv;
    }
    __syncthreads();
    for (int l = tid; l < 784; l += 256) {
        int which = l / 392, cc = (l % 392) / 49, n = l % 49;
        const float* p = &pl[which][cc * 48];
        float acc = 0.f;
        for (int t = 0; t < 48; ++t) acc += p[t] * tv[n * 48 + t];
        bf16* outp = which ? s_pre : d_pre;
        outp[(size_t)(b * 49 + n) * 64 + h * 8 + cc] = f2b(acc);
    }
}

// ---------------------------------------------------------------------------
extern "C" void kernel_launch(void* const* d_in, const int* in_sizes, int n_in,
                              void* d_out, int out_size, void* d_ws, size_t ws_size,
                              hipStream_t stream)
{
    const float* x          = (const float*)d_in[0];
    const float* x_ref      = (const float*)d_in[1];
    const float* dth_tok    = (const float*)d_in[2];
    const float* seg_tok    = (const float*)d_in[3];
    const float* qkv_w      = (const float*)d_in[4];
    const float* qkv_b      = (const float*)d_in[5];
    const float* proj_w     = (const float*)d_in[6];
    const float* proj_b     = (const float*)d_in[7];
    const float* rel_bias   = (const float*)d_in[8];
    const float* diff_mu    = (const float*)d_in[9];
    const float* diff_ls    = (const float*)d_in[10];
    const float* ref_qk_w   = (const float*)d_in[11];
    const float* ref_qk_b   = (const float*)d_in[12];
    const float* conv_w     = (const float*)d_in[13];
    const float* conv_b     = (const float*)d_in[14];
    const float* q_norm_w   = (const float*)d_in[15];
    const float* q_norm_b   = (const float*)d_in[16];
    const float* q_proj_w   = (const float*)d_in[17];
    const float* q_proj_b   = (const float*)d_in[18];
    const float* cls_dth_w  = (const float*)d_in[19];
    const float* cls_dth_b  = (const float*)d_in[20];
    const float* cls_seg_w  = (const float*)d_in[21];
    const float* cls_seg_b  = (const float*)d_in[22];
    const float* glob_k_w   = (const float*)d_in[23];
    const float* glob_k_b   = (const float*)d_in[24];
    const float* glob_v_w   = (const float*)d_in[25];
    const float* glob_v_b   = (const float*)d_in[26];
    const float* proj_dth_w = (const float*)d_in[27];
    const float* proj_dth_b = (const float*)d_in[28];

    // ---- workspace layout: total 65,274,368 B = 62.25 MiB ----
    bf16* wsb = (bf16*)d_ws;
    // Region A [0, 19267584) bf16: qkv; later t_k + t_v
    bf16* qkv      = wsb;
    bf16* t_k      = wsb;
    bf16* t_v      = wsb + 9633792;
    // Region B [19267584, 25690112) bf16: ref_attn -> attn_out -> {dq,sq,d_pre,s_pre}
    bf16* ref_attn = wsb + 19267584;
    bf16* attn_out = ref_attn;
    bf16* depth_q  = ref_attn;
    bf16* seg_q    = ref_attn + 1605632;
    bf16* d_pre    = ref_attn + 3211264;
    bf16* s_pre    = ref_attn + 4816896;
    // Region C [25690112, 32112640) bf16: u -> q_new
    bf16* u_buf    = wsb + 25690112;
    bf16* q_new    = u_buf;
    // Region D (f32 smalls) at byte offset 64,225,280
    float* ref_qk  = (float*)((char*)d_ws + 64225280);  // 131,072 f
    float* ref_q_t = ref_qk + 131072;                   //  65,536 f
    float* ref_v_t = ref_q_t + 65536;                   //  65,536 f
    float* stats   = ref_v_t + 65536;                   //     128 f

    float* out0  = (float*)d_out;           // [25088,256]
    float* out_d = out0 + 6422528;          // [25088,64]
    float* out_s = out0 + 8028160;          // [25088,64]

    // 1. qkv = x @ qkv_w + b  (bf16 ws out)
    gemm_kernel<<<dim3(12, 392), 256, 0, stream>>>(x, 0, nullptr, nullptr, qkv_w, qkv_b,
                                                   nullptr, qkv, 25088, 256, 768, 1.f);
    // 2. ref_qk = x_ref @ ref_qk_w + b  (f32 out, small)
    gemm_kernel<<<dim3(8, 4), 256, 0, stream>>>(x_ref, 0, nullptr, nullptr, ref_qk_w, ref_qk_b,
                                                ref_qk, nullptr, 256, 256, 512, 1.f);
    // 3. ref_q_t / ref_v_t
    refprep_kernel<<<256, 256, 0, stream>>>(ref_qk, diff_mu, diff_ls, ref_q_t, ref_v_t);
    // 4. ref_attn scores
    refattn_kernel<<<4096, 256, 0, stream>>>(qkv, ref_q_t, ref_attn);
    // 5. 3x diffusion: conv -> LN stats -> LN+gelu+residual
    for (int it = 0; it < 3; ++it) {
        conv_kernel<<<25088, 256, 0, stream>>>(ref_attn, conv_w, conv_b, u_buf);
        lnstats_kernel<<<64, 256, 0, stream>>>(u_buf, stats);
        lngelu_kernel<<<25088, 256, 0, stream>>>(u_buf, stats, ref_attn);
    }
    // 6. softmax @ ref_v + shortcut + LN + q_proj + residual, *SCALE -> q_new (C)
    qnew_kernel<<<25088, 256, 0, stream>>>(qkv, ref_attn, ref_v_t,
                                           q_norm_w, q_norm_b, q_proj_w, q_proj_b, q_new);
    // 7. window attention -> attn_out (B; ref_attn dead)
    winattn_kernel<<<4096, 256, 0, stream>>>(qkv, q_new, rel_bias, attn_out);
    // 8. out0 = attn_out @ proj_w + b  (f32, straight to d_out)
    gemm_kernel<<<dim3(4, 392), 256, 0, stream>>>(attn_out, 1, nullptr, nullptr, proj_w, proj_b,
                                                  out0, nullptr, 25088, 256, 256, 1.f);
    // 9/10. t_k, t_v from virtual concat(out0, dth, seg)  (A; qkv dead)
    gemm_kernel<<<dim3(6, 392), 256, 0, stream>>>(out0, 2, dth_tok, seg_tok, glob_k_w, glob_k_b,
                                                  nullptr, t_k, 25088, 384, 384, 1.f);
    gemm_kernel<<<dim3(6, 392), 256, 0, stream>>>(out0, 2, dth_tok, seg_tok, glob_v_w, glob_v_b,
                                                  nullptr, t_v, 25088, 384, 384, 1.f);
    // 11/12. depth_q, seg_q (scaled)  (B; attn_out dead)
    gemm_kernel<<<dim3(1, 392), 256, 0, stream>>>(dth_tok, 0, nullptr, nullptr, cls_dth_w, cls_dth_b,
                                                  nullptr, depth_q, 25088, 64, 64, SCALE_T);
    gemm_kernel<<<dim3(1, 392), 256, 0, stream>>>(seg_tok, 0, nullptr, nullptr, cls_seg_w, cls_seg_b,
                                                  nullptr, seg_q, 25088, 64, 64, SCALE_T);
    // 13. class-token attention
    clsattn_kernel<<<4096, 256, 0, stream>>>(t_k, t_v, depth_q, seg_q, d_pre, s_pre);
    // 14/15. final proj_dth for both tokens (f32 to d_out)
    gemm_kernel<<<dim3(1, 392), 256, 0, stream>>>(d_pre, 1, nullptr, nullptr, proj_dth_w, proj_dth_b,
                                                  out_d, nullptr, 25088, 64, 64, 1.f);
    gemm_kernel<<<dim3(1, 392), 256, 0, stream>>>(s_pre, 1, nullptr, nullptr, proj_dth_w, proj_dth_b,
                                                  out_s, nullptr, 25088, 64, 64, 1.f);
}

// Round 5
// 1319.260 us; speedup vs baseline: 1.6142x; 1.6142x over previous
//
#include <hip/hip_runtime.h>
#include <hip/hip_bf16.h>

typedef __hip_bfloat16 bf16;
typedef short s16x8 __attribute__((ext_vector_type(8)));
typedef float f32x4 __attribute__((ext_vector_type(4)));
union V16 { uint4 u4; s16x8 s8; };

static __device__ __forceinline__ float b2f(bf16 v){ return __bfloat162float(v); }
static __device__ __forceinline__ bf16  f2b(float v){ return __float2bfloat16(v); }
static __device__ __forceinline__ unsigned short f2bs(float x){
    union { float f; unsigned u; } c; c.f = x;
    unsigned r = c.u + 0x7fff + ((c.u >> 16) & 1);
    return (unsigned short)(r >> 16);
}

#define SCALE_T 0.17677669529663687f   // 32^-0.5

// ---------------------------------------------------------------------------
// MFMA bf16 GEMM: out = (A[M,K] @ W[K,N] + bias [+ add]) * scale
// 64x64 tile, BK=32, 256 threads (4 waves), v_mfma_f32_16x16x32_bf16.
// a_mode: 0 = A f32 [M,K]; 1 = A bf16 [M,K] (ws intermediate);
//         2 = A = concat(A f32[M,256], Xd f32[M,64], Xs f32[M,64]) (K=384)
// W/bias f32. addp: optional bf16 [M,addStride] residual added pre-scale.
// Writes outF (f32) and/or outB (bf16).  M%64==0, N%64==0, K%32==0.
// ---------------------------------------------------------------------------
__global__ __launch_bounds__(256) void mfma_gemm(
    const void* __restrict__ A, int a_mode,
    const float* __restrict__ Xd, const float* __restrict__ Xs,
    const float* __restrict__ W, const float* __restrict__ bias,
    const bf16* __restrict__ addp, int addStride,
    float* __restrict__ outF, bf16* __restrict__ outB,
    int M, int K, int N, float scale)
{
    __shared__ __hip_bfloat16 Al[64][48];   // [m][k], pad 32->48 (96B rows, 16B-aligned frags)
    __shared__ __hip_bfloat16 Bl[64][48];   // [n][k] (transposed W tile)

    const int tid  = threadIdx.x;
    const int wv   = tid >> 6, lane = tid & 63;
    const int quad = lane >> 4, l15 = lane & 15;
    const int rowBase = blockIdx.y * 64, colBase = blockIdx.x * 64;

    // A staging: thread -> row am, 8 consecutive k at ak
    const int am = tid >> 2, ak = (tid & 3) * 8;
    // B staging: thread -> col bn, 8 consecutive k at bk
    const int bn = tid & 63, bk = (tid >> 6) * 8;

    f32x4 acc[4];
    #pragma unroll
    for (int t = 0; t < 4; ++t)
        #pragma unroll
        for (int r = 0; r < 4; ++r) acc[t][r] = 0.f;

    for (int kt = 0; kt < K; kt += 32) {
        // ---- stage A tile ----
        s16x8 sa;
        if (a_mode == 1) {
            const bf16* Ab = (const bf16*)A;
            V16 u; u.u4 = *(const uint4*)(Ab + (size_t)(rowBase + am) * K + kt + ak);
            sa = u.s8;
        } else {
            const float* src; size_t base;
            if (a_mode == 0) {
                src = (const float*)A; base = (size_t)(rowBase + am) * K + kt + ak;
            } else {
                int kcol = kt + ak;
                if (kcol < 256)      { src = (const float*)A; base = (size_t)(rowBase + am) * 256 + kcol; }
                else if (kcol < 320) { src = Xd; base = (size_t)(rowBase + am) * 64 + (kcol - 256); }
                else                 { src = Xs; base = (size_t)(rowBase + am) * 64 + (kcol - 320); }
            }
            const float4* p = (const float4*)(src + base);
            float4 u0 = p[0], u1 = p[1];
            sa[0] = (short)f2bs(u0.x); sa[1] = (short)f2bs(u0.y);
            sa[2] = (short)f2bs(u0.z); sa[3] = (short)f2bs(u0.w);
            sa[4] = (short)f2bs(u1.x); sa[5] = (short)f2bs(u1.y);
            sa[6] = (short)f2bs(u1.z); sa[7] = (short)f2bs(u1.w);
        }
        *(s16x8*)&Al[am][ak] = sa;

        // ---- stage B tile (transpose W[k][n] -> Bl[n][k]) ----
        s16x8 sb;
        #pragma unroll
        for (int j = 0; j < 8; ++j)
            sb[j] = (short)f2bs(W[(size_t)(kt + bk + j) * N + colBase + bn]);
        *(s16x8*)&Bl[bn][bk] = sb;

        __syncthreads();

        s16x8 a = *(const s16x8*)&Al[wv * 16 + l15][quad * 8];
        #pragma unroll
        for (int t = 0; t < 4; ++t) {
            s16x8 b = *(const s16x8*)&Bl[t * 16 + l15][quad * 8];
            acc[t] = __builtin_amdgcn_mfma_f32_16x16x32_bf16(a, b, acc[t], 0, 0, 0);
        }
        __syncthreads();
    }

    // ---- epilogue: C/D layout col=lane&15, row=quad*4+reg ----
    #pragma unroll
    for (int t = 0; t < 4; ++t) {
        int col = colBase + t * 16 + l15;
        float bb = bias[col];
        #pragma unroll
        for (int r = 0; r < 4; ++r) {
            int row = rowBase + wv * 16 + quad * 4 + r;
            float v = acc[t][r] + bb;
            if (addp) v += b2f(addp[(size_t)row * addStride + col]);
            v *= scale;
            if (outF) outF[(size_t)row * N + col] = v;
            if (outB) outB[(size_t)row * N + col] = f2b(v);
        }
    }
}

// ---------------------------------------------------------------------------
// ref_q_t[r,h,f,d] = mu[c] + exp(ls[c]) * ref_qk[r*32+f, c];  ref_v_t from +256
// (c = h*32+d).  65536 threads.
// ---------------------------------------------------------------------------
__global__ __launch_bounds__(256) void refprep_kernel(
    const float* __restrict__ ref_qk, const float* __restrict__ mu,
    const float* __restrict__ ls, float* __restrict__ ref_q_t,
    float* __restrict__ ref_v_t)
{
    int idx = blockIdx.x * 256 + threadIdx.x;          // [r,h,f,d]
    int d = idx & 31, f = (idx >> 5) & 31, h = (idx >> 10) & 7, r = idx >> 13;
    int c = h * 32 + d;
    size_t src = (size_t)(r * 32 + f) * 512 + c;
    ref_q_t[idx] = mu[c] + __expf(ls[c]) * ref_qk[src];
    ref_v_t[idx] = ref_qk[src + 256];
}

// ---------------------------------------------------------------------------
// ref_attn[r,h,w,n,f] = sum_d (q[b,h,n,d]*SCALE) * ref_q_t[r,h,f,d]
// grid = 4096 blocks of 256.
// ---------------------------------------------------------------------------
__global__ __launch_bounds__(256) void refattn_kernel(
    const bf16* __restrict__ qkv, const float* __restrict__ ref_q_t,
    bf16* __restrict__ ref_attn)
{
    int blk = blockIdx.x;
    int w = blk & 63, h = (blk >> 6) & 7, r = blk >> 9;
    int b = r * 64 + w;
    __shared__ float qt[49 * 32];     // [n][d]
    __shared__ float rq[32 * 33];     // [f][d], padded
    int tid = threadIdx.x;
    for (int l = tid; l < 1568; l += 256) {
        int n = l >> 5, d = l & 31;
        qt[l] = b2f(qkv[(size_t)(b * 49 + n) * 768 + h * 32 + d]) * SCALE_T;
    }
    for (int l = tid; l < 1024; l += 256) {
        int f = l >> 5, d = l & 31;
        rq[f * 33 + d] = ref_q_t[(size_t)((r * 8 + h) * 32 + f) * 32 + d];
    }
    __syncthreads();
    for (int l = tid; l < 1568; l += 256) {
        int n = l >> 5, f = l & 31;
        float acc = 0.f;
        #pragma unroll
        for (int d2 = 0; d2 < 32; ++d2) acc += qt[n * 32 + d2] * rq[f * 33 + d2];
        ref_attn[(size_t)(((r * 8 + h) * 64 + w) * 49 + n) * 32 + f] = f2b(acc);
    }
}

// ---------------------------------------------------------------------------
// 3x3 SAME conv over [RB=8, 8ch, 3136, 32].  grid = 25088 blocks of 256.
// ---------------------------------------------------------------------------
__global__ __launch_bounds__(256) void conv_kernel(
    const bf16* __restrict__ in, const float* __restrict__ conv_w,
    const float* __restrict__ conv_b, bf16* __restrict__ u)
{
    __shared__ float w_s[576];
    __shared__ float b_s[8];
    int tid = threadIdx.x;
    for (int l = tid; l < 576; l += 256) w_s[l] = conv_w[l];
    if (tid < 8) b_s[tid] = conv_b[tid];
    __syncthreads();
    int idx = blockIdx.x * 256 + tid;          // < 6,422,528
    int f = idx & 31;
    int p = (idx >> 5) % 3136;
    int o = ((idx >> 5) / 3136) & 7;
    int r = idx / (32 * 3136 * 8);
    float acc = b_s[o];
    for (int i = 0; i < 8; ++i) {
        const bf16* ip = in + (size_t)(r * 8 + i) * 3136 * 32;
        #pragma unroll
        for (int ky = 0; ky < 3; ++ky) {
            int pp = p + ky - 1;
            if ((unsigned)pp >= 3136u) continue;
            #pragma unroll
            for (int kx = 0; kx < 3; ++kx) {
                int ff = f + kx - 1;
                if ((unsigned)ff >= 32u) continue;
                acc += b2f(ip[pp * 32 + ff]) * w_s[((o * 8 + i) * 3 + ky) * 3 + kx];
            }
        }
    }
    u[idx] = f2b(acc);
}

// ---------------------------------------------------------------------------
// Per-(r,ch) mean/rstd over contiguous 100352-elem map.  64 blocks.
// ---------------------------------------------------------------------------
__global__ __launch_bounds__(256) void lnstats_kernel(
    const bf16* __restrict__ u, float* __restrict__ stats)
{
    int g = blockIdx.x;
    const bf16* p = u + (size_t)g * 100352;
    int tid = threadIdx.x;
    float s = 0.f, s2 = 0.f;
    for (int i = tid; i < 100352; i += 256) { float v = b2f(p[i]); s += v; s2 += v * v; }
    __shared__ float r1[256], r2[256];
    r1[tid] = s; r2[tid] = s2; __syncthreads();
    for (int st = 128; st > 0; st >>= 1) {
        if (tid < st) { r1[tid] += r1[tid + st]; r2[tid] += r2[tid + st]; }
        __syncthreads();
    }
    if (tid == 0) {
        float mean = r1[0] * (1.f / 100352.f);
        float var  = r2[0] * (1.f / 100352.f) - mean * mean;
        var = fmaxf(var, 0.f);
        stats[g * 2] = mean;
        stats[g * 2 + 1] = rsqrtf(var + 1e-5f);
    }
}

// ref_attn += gelu_exact( (u - mean) * rstd );  grid = 25088 blocks.
__global__ __launch_bounds__(256) void lngelu_kernel(
    const bf16* __restrict__ u, const float* __restrict__ stats,
    bf16* __restrict__ ref_attn)
{
    int idx = blockIdx.x * 256 + threadIdx.x;
    int g = idx / 100352;
    float v = (b2f(u[idx]) - stats[g * 2]) * stats[g * 2 + 1];
    float ge = 0.5f * v * (1.f + erff(v * 0.7071067811865476f));
    ref_attn[idx] = f2b(b2f(ref_attn[idx]) + ge);
}

// ---------------------------------------------------------------------------
// Per (b,n): softmax(32) @ ref_v + q_sc, LN(256) -> ln_t (bf16).
// The q_proj GEMM + residual + scale is done by mfma_gemm afterwards.
// grid = 25088 blocks of 256 (tid = c = h*32+d).
// ---------------------------------------------------------------------------
__global__ __launch_bounds__(256) void qnew_pre_kernel(
    const bf16* __restrict__ qkv, const bf16* __restrict__ ref_attn,
    const float* __restrict__ ref_v_t,
    const float* __restrict__ qnw, const float* __restrict__ qnb,
    bf16* __restrict__ ln_t)
{
    int row = blockIdx.x;               // b*49+n
    int b = row / 49, n = row % 49;
    int r = b >> 6, w = b & 63;
    int tid = threadIdx.x, h = tid >> 5, d = tid & 31;
    __shared__ float s_logit[256], s_p[256], s_red[256];
    __shared__ float s_mean, s_rstd;

    s_logit[tid] = b2f(ref_attn[(size_t)(((r * 8 + h) * 64 + w) * 49 + n) * 32 + d]);
    __syncthreads();
    int base = h * 32;
    float mx = -1e30f;
    #pragma unroll
    for (int f = 0; f < 32; ++f) mx = fmaxf(mx, s_logit[base + f]);
    float sm = 0.f;
    #pragma unroll
    for (int f = 0; f < 32; ++f) sm += __expf(s_logit[base + f] - mx);
    s_p[tid] = __expf(s_logit[base + d] - mx) / sm;
    __syncthreads();

    float y = 0.f;
    const float* rv = ref_v_t + (size_t)((r * 8 + h) * 32) * 32 + d;
    #pragma unroll
    for (int f = 0; f < 32; ++f) y += s_p[base + f] * rv[f * 32];

    float qsc = b2f(qkv[(size_t)row * 768 + tid]);
    float z = y + qsc;

    s_red[tid] = z; __syncthreads();
    for (int st = 128; st > 0; st >>= 1) {
        if (tid < st) s_red[tid] += s_red[tid + st];
        __syncthreads();
    }
    if (tid == 0) s_mean = s_red[0] * (1.f / 256.f);
    __syncthreads();
    float zc = z - s_mean;
    s_red[tid] = zc * zc; __syncthreads();
    for (int st = 128; st > 0; st >>= 1) {
        if (tid < st) s_red[tid] += s_red[tid + st];
        __syncthreads();
    }
    if (tid == 0) s_rstd = rsqrtf(s_red[0] * (1.f / 256.f) + 1e-5f);
    __syncthreads();

    ln_t[(size_t)row * 256 + tid] = f2b(zc * s_rstd * qnw[tid] + qnb[tid]);
}

// ---------------------------------------------------------------------------
// Window attention per (b,h): softmax(q_new k^T + bias) @ v.  4096 blocks.
// ---------------------------------------------------------------------------
__global__ __launch_bounds__(256) void winattn_kernel(
    const bf16* __restrict__ qkv, const bf16* __restrict__ q_new,
    const float* __restrict__ rel_bias, bf16* __restrict__ attn_out)
{
    int bh = blockIdx.x;
    int b = bh >> 3, h = bh & 7;
    int tid = threadIdx.x;
    __shared__ float qn[1568], kk[1568], vv[1568], sc[49 * 50];
    for (int l = tid; l < 1568; l += 256) {
        int n = l >> 5, d = l & 31;
        size_t rq = (size_t)(b * 49 + n);
        qn[l] = b2f(q_new[rq * 256 + h * 32 + d]);
        kk[l] = b2f(qkv[rq * 768 + 256 + h * 32 + d]);
        vv[l] = b2f(qkv[rq * 768 + 512 + h * 32 + d]);
    }
    __syncthreads();
    for (int l = tid; l < 2401; l += 256) {
        int n = l / 49, m = l % 49;
        float acc = 0.f;
        #pragma unroll
        for (int d2 = 0; d2 < 32; ++d2) acc += qn[n * 32 + d2] * kk[m * 32 + d2];
        int ni = n / 7, nj = n % 7, mi = m / 7, mj = m % 7;
        int bidx = ((ni - mi + 6) * 13 + (nj - mj + 6)) * 8 + h;
        sc[n * 50 + m] = acc + rel_bias[bidx];
    }
    __syncthreads();
    if (tid < 49) {
        float mx = -1e30f;
        for (int m = 0; m < 49; ++m) mx = fmaxf(mx, sc[tid * 50 + m]);
        float s = 0.f;
        for (int m = 0; m < 49; ++m) { float e = __expf(sc[tid * 50 + m] - mx); sc[tid * 50 + m] = e; s += e; }
        float inv = 1.f / s;
        for (int m = 0; m < 49; ++m) sc[tid * 50 + m] *= inv;
    }
    __syncthreads();
    for (int l = tid; l < 1568; l += 256) {
        int n = l >> 5, d = l & 31;
        float acc = 0.f;
        for (int m = 0; m < 49; ++m) acc += sc[n * 50 + m] * vv[m * 32 + d];
        attn_out[(size_t)(b * 49 + n) * 256 + h * 32 + d] = f2b(acc);
    }
}

// ---------------------------------------------------------------------------
// Class-token attention per (b,h): both depth & seg.  4096 blocks.
// ---------------------------------------------------------------------------
__global__ __launch_bounds__(256) void clsattn_kernel(
    const bf16* __restrict__ t_k, const bf16* __restrict__ t_v,
    const bf16* __restrict__ depth_q, const bf16* __restrict__ seg_q,
    bf16* __restrict__ d_pre, bf16* __restrict__ s_pre)
{
    int bh = blockIdx.x;
    int b = bh >> 3, h = bh & 7;
    int tid = threadIdx.x;
    __shared__ float tk[2352], tv[2352], dq[392], sq[392], pl[2][384];
    for (int l = tid; l < 2352; l += 256) {
        int n = l / 48, t = l % 48;
        size_t row = (size_t)(b * 49 + n);
        tk[l] = b2f(t_k[row * 384 + h * 48 + t]);
        tv[l] = b2f(t_v[row * 384 + h * 48 + t]);
    }
    for (int l = tid; l < 392; l += 256) {
        int n = l / 8, c = l % 8;
        size_t row = (size_t)(b * 49 + n);
        dq[l] = b2f(depth_q[row * 64 + h * 8 + c]);
        sq[l] = b2f(seg_q[row * 64 + h * 8 + c]);
    }
    __syncthreads();
    for (int l = tid; l < 768; l += 256) {
        int which = l / 384, cc = (l % 384) / 48, t = l % 48;
        const float* q = which ? sq : dq;
        float acc = 0.f;
        for (int n = 0; n < 49; ++n) acc += q[n * 8 + cc] * tk[n * 48 + t];
        pl[which][cc * 48 + t] = acc;
    }
    __syncthreads();
    if (tid < 16) {
        int which = tid >> 3, cc = tid & 7;
        float* p = &pl[which][cc * 48];
        float mx = -1e30f;
        for (int t = 0; t < 48; ++t) mx = fmaxf(mx, p[t]);
        float s = 0.f;
        for (int t = 0; t < 48; ++t) { float e = __expf(p[t] - mx); p[t] = e; s += e; }
        float inv = 1.f / s;
        for (int t = 0; t < 48; ++t) p[t] *= inv;
    }
    __syncthreads();
    for (int l = tid; l < 784; l += 256) {
        int which = l / 392, cc = (l % 392) / 49, n = l % 49;
        const float* p = &pl[which][cc * 48];
        float acc = 0.f;
        for (int t = 0; t < 48; ++t) acc += p[t] * tv[n * 48 + t];
        bf16* outp = which ? s_pre : d_pre;
        outp[(size_t)(b * 49 + n) * 64 + h * 8 + cc] = f2b(acc);
    }
}

// ---------------------------------------------------------------------------
extern "C" void kernel_launch(void* const* d_in, const int* in_sizes, int n_in,
                              void* d_out, int out_size, void* d_ws, size_t ws_size,
                              hipStream_t stream)
{
    const float* x          = (const float*)d_in[0];
    const float* x_ref      = (const float*)d_in[1];
    const float* dth_tok    = (const float*)d_in[2];
    const float* seg_tok    = (const float*)d_in[3];
    const float* qkv_w      = (const float*)d_in[4];
    const float* qkv_b      = (const float*)d_in[5];
    const float* proj_w     = (const float*)d_in[6];
    const float* proj_b     = (const float*)d_in[7];
    const float* rel_bias   = (const float*)d_in[8];
    const float* diff_mu    = (const float*)d_in[9];
    const float* diff_ls    = (const float*)d_in[10];
    const float* ref_qk_w   = (const float*)d_in[11];
    const float* ref_qk_b   = (const float*)d_in[12];
    const float* conv_w     = (const float*)d_in[13];
    const float* conv_b     = (const float*)d_in[14];
    const float* q_norm_w   = (const float*)d_in[15];
    const float* q_norm_b   = (const float*)d_in[16];
    const float* q_proj_w   = (const float*)d_in[17];
    const float* q_proj_b   = (const float*)d_in[18];
    const float* cls_dth_w  = (const float*)d_in[19];
    const float* cls_dth_b  = (const float*)d_in[20];
    const float* cls_seg_w  = (const float*)d_in[21];
    const float* cls_seg_b  = (const float*)d_in[22];
    const float* glob_k_w   = (const float*)d_in[23];
    const float* glob_k_b   = (const float*)d_in[24];
    const float* glob_v_w   = (const float*)d_in[25];
    const float* glob_v_b   = (const float*)d_in[26];
    const float* proj_dth_w = (const float*)d_in[27];
    const float* proj_dth_b = (const float*)d_in[28];

    // ---- workspace layout: total 62.25 MiB ----
    bf16* wsb = (bf16*)d_ws;
    // Region A [0, 19267584) bf16: qkv; later t_k + t_v
    bf16* qkv      = wsb;
    bf16* t_k      = wsb;
    bf16* t_v      = wsb + 9633792;
    // Region B [19267584, 25690112) bf16: ref_attn -> q_new -> {dq,sq,d_pre,s_pre}
    bf16* ref_attn = wsb + 19267584;
    bf16* q_new    = ref_attn;
    bf16* depth_q  = ref_attn;
    bf16* seg_q    = ref_attn + 1605632;
    bf16* d_pre    = ref_attn + 3211264;
    bf16* s_pre    = ref_attn + 4816896;
    // Region C [25690112, 32112640) bf16: u_buf -> ln_t -> attn_out
    bf16* u_buf    = wsb + 25690112;
    bf16* ln_t     = u_buf;
    bf16* attn_out = u_buf;
    // Region D (f32 smalls) at byte offset 64,225,280
    float* ref_qk  = (float*)((char*)d_ws + 64225280);  // 131,072 f
    float* ref_q_t = ref_qk + 131072;                   //  65,536 f
    float* ref_v_t = ref_q_t + 65536;                   //  65,536 f
    float* stats   = ref_v_t + 65536;                   //     128 f

    float* out0  = (float*)d_out;           // [25088,256]
    float* out_d = out0 + 6422528;          // [25088,64]
    float* out_s = out0 + 8028160;          // [25088,64]

    // 1. qkv = x @ qkv_w + b  (bf16 ws out)
    mfma_gemm<<<dim3(12, 392), 256, 0, stream>>>(x, 0, nullptr, nullptr, qkv_w, qkv_b,
                                                 nullptr, 0, nullptr, qkv, 25088, 256, 768, 1.f);
    // 2. ref_qk = x_ref @ ref_qk_w + b  (f32 out, small)
    mfma_gemm<<<dim3(8, 4), 256, 0, stream>>>(x_ref, 0, nullptr, nullptr, ref_qk_w, ref_qk_b,
                                              nullptr, 0, ref_qk, nullptr, 256, 256, 512, 1.f);
    // 3. ref_q_t / ref_v_t
    refprep_kernel<<<256, 256, 0, stream>>>(ref_qk, diff_mu, diff_ls, ref_q_t, ref_v_t);
    // 4. ref_attn scores -> B
    refattn_kernel<<<4096, 256, 0, stream>>>(qkv, ref_q_t, ref_attn);
    // 5. 3x diffusion: conv -> LN stats -> LN+gelu+residual  (u in C)
    for (int it = 0; it < 3; ++it) {
        conv_kernel<<<25088, 256, 0, stream>>>(ref_attn, conv_w, conv_b, u_buf);
        lnstats_kernel<<<64, 256, 0, stream>>>(u_buf, stats);
        lngelu_kernel<<<25088, 256, 0, stream>>>(u_buf, stats, ref_attn);
    }
    // 6. softmax @ ref_v + shortcut + LN -> ln_t (C; u dead)
    qnew_pre_kernel<<<25088, 256, 0, stream>>>(qkv, ref_attn, ref_v_t,
                                               q_norm_w, q_norm_b, ln_t);
    // 7. q_new = (ln_t @ q_proj_w + q_proj_b + qsc) * SCALE -> B (ref_attn dead)
    mfma_gemm<<<dim3(4, 392), 256, 0, stream>>>(ln_t, 1, nullptr, nullptr, q_proj_w, q_proj_b,
                                                qkv, 768, nullptr, q_new, 25088, 256, 256, SCALE_T);
    // 8. window attention -> attn_out (C; ln_t dead)
    winattn_kernel<<<4096, 256, 0, stream>>>(qkv, q_new, rel_bias, attn_out);
    // 9. out0 = attn_out @ proj_w + b  (f32, straight to d_out)
    mfma_gemm<<<dim3(4, 392), 256, 0, stream>>>(attn_out, 1, nullptr, nullptr, proj_w, proj_b,
                                                nullptr, 0, out0, nullptr, 25088, 256, 256, 1.f);
    // 10/11. t_k, t_v from virtual concat(out0, dth, seg)  (A; qkv dead)
    mfma_gemm<<<dim3(6, 392), 256, 0, stream>>>(out0, 2, dth_tok, seg_tok, glob_k_w, glob_k_b,
                                                nullptr, 0, nullptr, t_k, 25088, 384, 384, 1.f);
    mfma_gemm<<<dim3(6, 392), 256, 0, stream>>>(out0, 2, dth_tok, seg_tok, glob_v_w, glob_v_b,
                                                nullptr, 0, nullptr, t_v, 25088, 384, 384, 1.f);
    // 12/13. depth_q, seg_q (scaled)  (B; q_new dead)
    mfma_gemm<<<dim3(1, 392), 256, 0, stream>>>(dth_tok, 0, nullptr, nullptr, cls_dth_w, cls_dth_b,
                                                nullptr, 0, nullptr, depth_q, 25088, 64, 64, SCALE_T);
    mfma_gemm<<<dim3(1, 392), 256, 0, stream>>>(seg_tok, 0, nullptr, nullptr, cls_seg_w, cls_seg_b,
                                                nullptr, 0, nullptr, seg_q, 25088, 64, 64, SCALE_T);
    // 14. class-token attention
    clsattn_kernel<<<4096, 256, 0, stream>>>(t_k, t_v, depth_q, seg_q, d_pre, s_pre);
    // 15/16. final proj_dth for both tokens (f32 to d_out)
    mfma_gemm<<<dim3(1, 392), 256, 0, stream>>>(d_pre, 1, nullptr, nullptr, proj_dth_w, proj_dth_b,
                                                nullptr, 0, out_d, nullptr, 25088, 64, 64, 1.f);
    mfma_gemm<<<dim3(1, 392), 256, 0, stream>>>(s_pre, 1, nullptr, nullptr, proj_dth_w, proj_dth_b,
                                                nullptr, 0, out_s, nullptr, 25088, 64, 64, 1.f);
}

// Round 6
// 702.257 us; speedup vs baseline: 3.0325x; 1.8786x over previous
//
#include <hip/hip_runtime.h>
#include <hip/hip_bf16.h>

typedef __hip_bfloat16 bf16;
typedef short s16x8 __attribute__((ext_vector_type(8)));
typedef float f32x4 __attribute__((ext_vector_type(4)));
union V16 { uint4 u4; s16x8 s8; unsigned u[4]; };

static __device__ __forceinline__ float b2f(bf16 v){ return __bfloat162float(v); }
static __device__ __forceinline__ bf16  f2b(float v){ return __float2bfloat16(v); }
static __device__ __forceinline__ unsigned short f2bs(float x){
    union { float f; unsigned u; } c; c.f = x;
    unsigned r = c.u + 0x7fff + ((c.u >> 16) & 1);
    return (unsigned short)(r >> 16);
}
static __device__ __forceinline__ float bu2f(unsigned short b){
    union { unsigned u; float f; } c; c.u = ((unsigned)b) << 16; return c.f;
}

#define SCALE_T 0.17677669529663687f   // 32^-0.5

// ---------------------------------------------------------------------------
// MFMA bf16 GEMM: out = (A[M,K] @ W[K,N] + bias [+ add]) * scale
// 64x64 tile, BK=32, 256 threads (4 waves), v_mfma_f32_16x16x32_bf16.
// a_mode: 0 = A f32 [M,K]; 1 = A bf16 [M,K] (ws intermediate);
//         2 = A = concat(A f32[M,256], Xd f32[M,64], Xs f32[M,64]) (K=384)
// ---------------------------------------------------------------------------
__global__ __launch_bounds__(256) void mfma_gemm(
    const void* __restrict__ A, int a_mode,
    const float* __restrict__ Xd, const float* __restrict__ Xs,
    const float* __restrict__ W, const float* __restrict__ bias,
    const bf16* __restrict__ addp, int addStride,
    float* __restrict__ outF, bf16* __restrict__ outB,
    int M, int K, int N, float scale)
{
    __shared__ __hip_bfloat16 Al[64][48];
    __shared__ __hip_bfloat16 Bl[64][48];

    const int tid  = threadIdx.x;
    const int wv   = tid >> 6, lane = tid & 63;
    const int quad = lane >> 4, l15 = lane & 15;
    const int rowBase = blockIdx.y * 64, colBase = blockIdx.x * 64;

    const int am = tid >> 2, ak = (tid & 3) * 8;
    const int bn = tid & 63, bk = (tid >> 6) * 8;

    f32x4 acc[4];
    #pragma unroll
    for (int t = 0; t < 4; ++t)
        #pragma unroll
        for (int r = 0; r < 4; ++r) acc[t][r] = 0.f;

    for (int kt = 0; kt < K; kt += 32) {
        s16x8 sa;
        if (a_mode == 1) {
            const bf16* Ab = (const bf16*)A;
            V16 u; u.u4 = *(const uint4*)(Ab + (size_t)(rowBase + am) * K + kt + ak);
            sa = u.s8;
        } else {
            const float* src; size_t base;
            if (a_mode == 0) {
                src = (const float*)A; base = (size_t)(rowBase + am) * K + kt + ak;
            } else {
                int kcol = kt + ak;
                if (kcol < 256)      { src = (const float*)A; base = (size_t)(rowBase + am) * 256 + kcol; }
                else if (kcol < 320) { src = Xd; base = (size_t)(rowBase + am) * 64 + (kcol - 256); }
                else                 { src = Xs; base = (size_t)(rowBase + am) * 64 + (kcol - 320); }
            }
            const float4* p = (const float4*)(src + base);
            float4 u0 = p[0], u1 = p[1];
            sa[0] = (short)f2bs(u0.x); sa[1] = (short)f2bs(u0.y);
            sa[2] = (short)f2bs(u0.z); sa[3] = (short)f2bs(u0.w);
            sa[4] = (short)f2bs(u1.x); sa[5] = (short)f2bs(u1.y);
            sa[6] = (short)f2bs(u1.z); sa[7] = (short)f2bs(u1.w);
        }
        *(s16x8*)&Al[am][ak] = sa;

        s16x8 sb;
        #pragma unroll
        for (int j = 0; j < 8; ++j)
            sb[j] = (short)f2bs(W[(size_t)(kt + bk + j) * N + colBase + bn]);
        *(s16x8*)&Bl[bn][bk] = sb;

        __syncthreads();

        s16x8 a = *(const s16x8*)&Al[wv * 16 + l15][quad * 8];
        #pragma unroll
        for (int t = 0; t < 4; ++t) {
            s16x8 b = *(const s16x8*)&Bl[t * 16 + l15][quad * 8];
            acc[t] = __builtin_amdgcn_mfma_f32_16x16x32_bf16(a, b, acc[t], 0, 0, 0);
        }
        __syncthreads();
    }

    #pragma unroll
    for (int t = 0; t < 4; ++t) {
        int col = colBase + t * 16 + l15;
        float bb = bias[col];
        #pragma unroll
        for (int r = 0; r < 4; ++r) {
            int row = rowBase + wv * 16 + quad * 4 + r;
            float v = acc[t][r] + bb;
            if (addp) v += b2f(addp[(size_t)row * addStride + col]);
            v *= scale;
            if (outF) outF[(size_t)row * N + col] = v;
            if (outB) outB[(size_t)row * N + col] = f2b(v);
        }
    }
}

// ---------------------------------------------------------------------------
// ref_q_t[r,h,f,d] = mu[c] + exp(ls[c]) * ref_qk[r*32+f, c];  ref_v_t from +256
// ---------------------------------------------------------------------------
__global__ __launch_bounds__(256) void refprep_kernel(
    const float* __restrict__ ref_qk, const float* __restrict__ mu,
    const float* __restrict__ ls, float* __restrict__ ref_q_t,
    float* __restrict__ ref_v_t)
{
    int idx = blockIdx.x * 256 + threadIdx.x;          // [r,h,f,d]
    int d = idx & 31, f = (idx >> 5) & 31, h = (idx >> 10) & 7, r = idx >> 13;
    int c = h * 32 + d;
    size_t src = (size_t)(r * 32 + f) * 512 + c;
    ref_q_t[idx] = mu[c] + __expf(ls[c]) * ref_qk[src];
    ref_v_t[idx] = ref_qk[src + 256];
}

// ---------------------------------------------------------------------------
// ref_attn[r,h,w,n,f] = sum_d (q[b,h,n,d]*SCALE) * ref_q_t[r,h,f,d]
// ---------------------------------------------------------------------------
__global__ __launch_bounds__(256) void refattn_kernel(
    const bf16* __restrict__ qkv, const float* __restrict__ ref_q_t,
    bf16* __restrict__ ref_attn)
{
    int blk = blockIdx.x;
    int w = blk & 63, h = (blk >> 6) & 7, r = blk >> 9;
    int b = r * 64 + w;
    __shared__ float qt[49 * 32];
    __shared__ float rq[32 * 33];
    int tid = threadIdx.x;
    for (int l = tid; l < 1568; l += 256) {
        int n = l >> 5, d = l & 31;
        qt[l] = b2f(qkv[(size_t)(b * 49 + n) * 768 + h * 32 + d]) * SCALE_T;
    }
    for (int l = tid; l < 1024; l += 256) {
        int f = l >> 5, d = l & 31;
        rq[f * 33 + d] = ref_q_t[(size_t)((r * 8 + h) * 32 + f) * 32 + d];
    }
    __syncthreads();
    for (int l = tid; l < 1568; l += 256) {
        int n = l >> 5, f = l & 31;
        float acc = 0.f;
        #pragma unroll
        for (int d2 = 0; d2 < 32; ++d2) acc += qt[n * 32 + d2] * rq[f * 33 + d2];
        ref_attn[(size_t)(((r * 8 + h) * 64 + w) * 49 + n) * 32 + f] = f2b(acc);
    }
}

// ---------------------------------------------------------------------------
// 3x3 SAME conv over [RB=8, 8ch, 3136, 32].
// One thread = all 8 out-channels x 8-wide f vector at one (r,p).
// grid = 392 blocks of 256 (100,352 threads).
// ---------------------------------------------------------------------------
__global__ __launch_bounds__(256) void conv_kernel(
    const bf16* __restrict__ in, const float* __restrict__ conv_w,
    const float* __restrict__ conv_b, bf16* __restrict__ u)
{
    __shared__ float w_s[576];
    __shared__ float b_s[8];
    int tid = threadIdx.x;
    for (int l = tid; l < 576; l += 256) w_s[l] = conv_w[l];
    if (tid < 8) b_s[tid] = conv_b[tid];
    __syncthreads();

    int idx = blockIdx.x * 256 + tid;          // < 100352
    int fb = idx & 3;
    int p  = (idx >> 2) % 3136;
    int r  = idx / 12544;
    int f0 = fb * 8;

    float acc[8][8];
    #pragma unroll
    for (int o = 0; o < 8; ++o) {
        float bo = b_s[o];
        #pragma unroll
        for (int f = 0; f < 8; ++f) acc[o][f] = bo;
    }

    for (int i = 0; i < 8; ++i) {
        float ext[3][10];
        #pragma unroll
        for (int dy = 0; dy < 3; ++dy) {
            int pp = p + dy - 1;
            bool pv = (unsigned)pp < 3136u;
            size_t base = ((size_t)((r * 8 + i) * 3136 + (pv ? pp : 0))) * 32 + f0;
            V16 uv;
            uv.u4 = pv ? *(const uint4*)(in + base) : make_uint4(0, 0, 0, 0);
            #pragma unroll
            for (int j = 0; j < 8; ++j) {
                unsigned sh = uv.u[j >> 1];
                unsigned bits = (j & 1) ? (sh & 0xffff0000u) : (sh << 16);
                union { unsigned uu; float fl; } cv; cv.uu = bits;
                ext[dy][j + 1] = cv.fl;
            }
            ext[dy][0] = (pv && f0 > 0)      ? b2f(in[base - 1]) : 0.f;
            ext[dy][9] = (pv && f0 + 8 < 32) ? b2f(in[base + 8]) : 0.f;
        }
        #pragma unroll
        for (int o = 0; o < 8; ++o) {
            #pragma unroll
            for (int ky = 0; ky < 3; ++ky) {
                const float* wp = &w_s[((o * 8 + i) * 3 + ky) * 3];
                float w0 = wp[0], w1 = wp[1], w2 = wp[2];
                #pragma unroll
                for (int f = 0; f < 8; ++f)
                    acc[o][f] += ext[ky][f] * w0 + ext[ky][f + 1] * w1 + ext[ky][f + 2] * w2;
            }
        }
    }

    #pragma unroll
    for (int o = 0; o < 8; ++o) {
        bf16 ov[8];
        #pragma unroll
        for (int f = 0; f < 8; ++f) ov[f] = f2b(acc[o][f]);
        *(uint4*)(u + ((size_t)((r * 8 + o) * 3136 + p)) * 32 + f0) = *(uint4*)ov;
    }
}

// ---------------------------------------------------------------------------
// Per-(r,ch) mean/rstd over contiguous 100352-elem map.  64 blocks, bf16x8.
// ---------------------------------------------------------------------------
__global__ __launch_bounds__(256) void lnstats_kernel(
    const bf16* __restrict__ u, float* __restrict__ stats)
{
    int g = blockIdx.x;
    const bf16* p = u + (size_t)g * 100352;
    int tid = threadIdx.x;
    float s = 0.f, s2 = 0.f;
    for (int it = tid; it < 12544; it += 256) {
        V16 uv; uv.u4 = *(const uint4*)(p + it * 8);
        #pragma unroll
        for (int j = 0; j < 8; ++j) {
            unsigned sh = uv.u[j >> 1];
            unsigned bits = (j & 1) ? (sh & 0xffff0000u) : (sh << 16);
            union { unsigned uu; float fl; } cv; cv.uu = bits;
            s += cv.fl; s2 += cv.fl * cv.fl;
        }
    }
    __shared__ float r1[256], r2[256];
    r1[tid] = s; r2[tid] = s2; __syncthreads();
    for (int st = 128; st > 0; st >>= 1) {
        if (tid < st) { r1[tid] += r1[tid + st]; r2[tid] += r2[tid + st]; }
        __syncthreads();
    }
    if (tid == 0) {
        float mean = r1[0] * (1.f / 100352.f);
        float var  = r2[0] * (1.f / 100352.f) - mean * mean;
        var = fmaxf(var, 0.f);
        stats[g * 2] = mean;
        stats[g * 2 + 1] = rsqrtf(var + 1e-5f);
    }
}

// ref_attn += gelu_exact( (u - mean) * rstd );  bf16x8, grid = 3136 blocks.
__global__ __launch_bounds__(256) void lngelu_kernel(
    const bf16* __restrict__ u, const float* __restrict__ stats,
    bf16* __restrict__ ref_attn)
{
    int idx8 = blockIdx.x * 256 + threadIdx.x;    // < 802816
    int g = idx8 / 12544;
    size_t base = (size_t)idx8 * 8;
    float mean = stats[g * 2], rstd = stats[g * 2 + 1];
    V16 uv; uv.u4 = *(const uint4*)(u + base);
    V16 rv; rv.u4 = *(const uint4*)(ref_attn + base);
    bf16 outv[8];
    #pragma unroll
    for (int j = 0; j < 8; ++j) {
        unsigned shu = uv.u[j >> 1];
        unsigned shr = rv.u[j >> 1];
        unsigned bu = (j & 1) ? (shu & 0xffff0000u) : (shu << 16);
        unsigned br = (j & 1) ? (shr & 0xffff0000u) : (shr << 16);
        union { unsigned uu; float fl; } cu, cr; cu.uu = bu; cr.uu = br;
        float v = (cu.fl - mean) * rstd;
        float ge = 0.5f * v * (1.f + erff(v * 0.7071067811865476f));
        outv[j] = f2b(cr.fl + ge);
    }
    *(uint4*)(ref_attn + base) = *(uint4*)outv;
}

// ---------------------------------------------------------------------------
// qnew_pre: per row (b,n): softmax(32)@ref_v + q_sc, LN(256) -> ln_t (bf16).
// One WAVE per row, no LDS, no barriers.  grid = 6272 blocks of 256 (4 rows).
// Lane owns 4 channels c = lane*4..+3; head h = lane>>3; 8-lane head groups.
// ---------------------------------------------------------------------------
__global__ __launch_bounds__(256) void qnew_pre_kernel(
    const bf16* __restrict__ qkv, const bf16* __restrict__ ref_attn,
    const float* __restrict__ ref_v_t,
    const float* __restrict__ qnw, const float* __restrict__ qnb,
    bf16* __restrict__ ln_t)
{
    int ww = threadIdx.x >> 6, lane = threadIdx.x & 63;
    int row = blockIdx.x * 4 + ww;            // < 25088
    int b = row / 49, n = row % 49;
    int r = b >> 6, w = b & 63;
    int h = lane >> 3, d0 = (lane & 7) * 4;

    // logits (4 contiguous f of this head)
    const bf16* la = ref_attn + ((size_t)(((r * 8 + h) * 64 + w) * 49 + n)) * 32 + d0;
    ushort4 lu = *(const ushort4*)la;
    float lg[4] = { bu2f(lu.x), bu2f(lu.y), bu2f(lu.z), bu2f(lu.w) };

    // softmax over 32 within 8-lane head group
    float m = fmaxf(fmaxf(lg[0], lg[1]), fmaxf(lg[2], lg[3]));
    m = fmaxf(m, __shfl_xor(m, 1));
    m = fmaxf(m, __shfl_xor(m, 2));
    m = fmaxf(m, __shfl_xor(m, 4));
    float p[4], s = 0.f;
    #pragma unroll
    for (int j = 0; j < 4; ++j) { p[j] = __expf(lg[j] - m); s += p[j]; }
    s += __shfl_xor(s, 1);
    s += __shfl_xor(s, 2);
    s += __shfl_xor(s, 4);
    float inv = 1.f / s;
    #pragma unroll
    for (int j = 0; j < 4; ++j) p[j] *= inv;

    // y[d] = sum_f p[f] * ref_v_t[r,h,f,d]
    const float* rv = ref_v_t + ((size_t)(r * 8 + h) * 32) * 32 + d0;
    float y[4] = {0.f, 0.f, 0.f, 0.f};
    #pragma unroll
    for (int f = 0; f < 32; ++f) {
        int src = (lane & 56) | (f >> 2);
        float pf = __shfl(p[f & 3], src);
        float4 rvf = *(const float4*)(rv + f * 32);
        y[0] += pf * rvf.x; y[1] += pf * rvf.y;
        y[2] += pf * rvf.z; y[3] += pf * rvf.w;
    }

    // + unscaled q shortcut
    ushort4 qu = *(const ushort4*)(qkv + (size_t)row * 768 + lane * 4);
    float z[4] = { y[0] + bu2f(qu.x), y[1] + bu2f(qu.y),
                   y[2] + bu2f(qu.z), y[3] + bu2f(qu.w) };

    // LN over 256 across the wave
    float s1 = z[0] + z[1] + z[2] + z[3];
    #pragma unroll
    for (int off = 1; off < 64; off <<= 1) s1 += __shfl_xor(s1, off);
    float mean = s1 * (1.f / 256.f);
    float zc[4] = { z[0] - mean, z[1] - mean, z[2] - mean, z[3] - mean };
    float s2 = zc[0]*zc[0] + zc[1]*zc[1] + zc[2]*zc[2] + zc[3]*zc[3];
    #pragma unroll
    for (int off = 1; off < 64; off <<= 1) s2 += __shfl_xor(s2, off);
    float rstd = rsqrtf(s2 * (1.f / 256.f) + 1e-5f);

    float4 wv = *(const float4*)(qnw + lane * 4);
    float4 bv = *(const float4*)(qnb + lane * 4);
    bf16 outv[4];
    outv[0] = f2b(zc[0] * rstd * wv.x + bv.x);
    outv[1] = f2b(zc[1] * rstd * wv.y + bv.y);
    outv[2] = f2b(zc[2] * rstd * wv.z + bv.z);
    outv[3] = f2b(zc[3] * rstd * wv.w + bv.w);
    *(ushort4*)(ln_t + (size_t)row * 256 + lane * 4) = *(ushort4*)outv;
}

// ---------------------------------------------------------------------------
// Window attention per (b,h): softmax(q_new k^T + bias) @ v.  4096 blocks.
// ---------------------------------------------------------------------------
__global__ __launch_bounds__(256) void winattn_kernel(
    const bf16* __restrict__ qkv, const bf16* __restrict__ q_new,
    const float* __restrict__ rel_bias, bf16* __restrict__ attn_out)
{
    int bh = blockIdx.x;
    int b = bh >> 3, h = bh & 7;
    int tid = threadIdx.x;
    __shared__ float qn[1568], kk[1568], vv[1568], sc[49 * 50];
    for (int l = tid; l < 1568; l += 256) {
        int n = l >> 5, d = l & 31;
        size_t rq = (size_t)(b * 49 + n);
        qn[l] = b2f(q_new[rq * 256 + h * 32 + d]);
        kk[l] = b2f(qkv[rq * 768 + 256 + h * 32 + d]);
        vv[l] = b2f(qkv[rq * 768 + 512 + h * 32 + d]);
    }
    __syncthreads();
    for (int l = tid; l < 2401; l += 256) {
        int n = l / 49, m = l % 49;
        float acc = 0.f;
        #pragma unroll
        for (int d2 = 0; d2 < 32; ++d2) acc += qn[n * 32 + d2] * kk[m * 32 + d2];
        int ni = n / 7, nj = n % 7, mi = m / 7, mj = m % 7;
        int bidx = ((ni - mi + 6) * 13 + (nj - mj + 6)) * 8 + h;
        sc[n * 50 + m] = acc + rel_bias[bidx];
    }
    __syncthreads();
    if (tid < 49) {
        float mx = -1e30f;
        for (int m = 0; m < 49; ++m) mx = fmaxf(mx, sc[tid * 50 + m]);
        float s = 0.f;
        for (int m = 0; m < 49; ++m) { float e = __expf(sc[tid * 50 + m] - mx); sc[tid * 50 + m] = e; s += e; }
        float inv = 1.f / s;
        for (int m = 0; m < 49; ++m) sc[tid * 50 + m] *= inv;
    }
    __syncthreads();
    for (int l = tid; l < 1568; l += 256) {
        int n = l >> 5, d = l & 31;
        float acc = 0.f;
        for (int m = 0; m < 49; ++m) acc += sc[n * 50 + m] * vv[m * 32 + d];
        attn_out[(size_t)(b * 49 + n) * 256 + h * 32 + d] = f2b(acc);
    }
}

// ---------------------------------------------------------------------------
// Class-token attention per (b,h): both depth & seg.  4096 blocks.
// ---------------------------------------------------------------------------
__global__ __launch_bounds__(256) void clsattn_kernel(
    const bf16* __restrict__ t_k, const bf16* __restrict__ t_v,
    const bf16* __restrict__ depth_q, const bf16* __restrict__ seg_q,
    bf16* __restrict__ d_pre, bf16* __restrict__ s_pre)
{
    int bh = blockIdx.x;
    int b = bh >> 3, h = bh & 7;
    int tid = threadIdx.x;
    __shared__ float tk[2352], tv[2352], dq[392], sq[392], pl[2][384];
    for (int l = tid; l < 2352; l += 256) {
        int n = l / 48, t = l % 48;
        size_t row = (size_t)(b * 49 + n);
        tk[l] = b2f(t_k[row * 384 + h * 48 + t]);
        tv[l] = b2f(t_v[row * 384 + h * 48 + t]);
    }
    for (int l = tid; l < 392; l += 256) {
        int n = l / 8, c = l % 8;
        size_t row = (size_t)(b * 49 + n);
        dq[l] = b2f(depth_q[row * 64 + h * 8 + c]);
        sq[l] = b2f(seg_q[row * 64 + h * 8 + c]);
    }
    __syncthreads();
    for (int l = tid; l < 768; l += 256) {
        int which = l / 384, cc = (l % 384) / 48, t = l % 48;
        const float* q = which ? sq : dq;
        float acc = 0.f;
        for (int n = 0; n < 49; ++n) acc += q[n * 8 + cc] * tk[n * 48 + t];
        pl[which][cc * 48 + t] = acc;
    }
    __syncthreads();
    if (tid < 16) {
        int which = tid >> 3, cc = tid & 7;
        float* p = &pl[which][cc * 48];
        float mx = -1e30f;
        for (int t = 0; t < 48; ++t) mx = fmaxf(mx, p[t]);
        float s = 0.f;
        for (int t = 0; t < 48; ++t) { float e = __expf(p[t] - mx); p[t] = e; s += e; }
        float inv = 1.f / s;
        for (int t = 0; t < 48; ++t) p[t] *= inv;
    }
    __syncthreads();
    for (int l = tid; l < 784; l += 256) {
        int which = l / 392, cc = (l % 392) / 49, n = l % 49;
        const float* p = &pl[which][cc * 48];
        float acc = 0.f;
        for (int t = 0; t < 48; ++t) acc += p[t] * tv[n * 48 + t];
        bf16* outp = which ? s_pre : d_pre;
        outp[(size_t)(b * 49 + n) * 64 + h * 8 + cc] = f2b(acc);
    }
}

// ---------------------------------------------------------------------------
extern "C" void kernel_launch(void* const* d_in, const int* in_sizes, int n_in,
                              void* d_out, int out_size, void* d_ws, size_t ws_size,
                              hipStream_t stream)
{
    const float* x          = (const float*)d_in[0];
    const float* x_ref      = (const float*)d_in[1];
    const float* dth_tok    = (const float*)d_in[2];
    const float* seg_tok    = (const float*)d_in[3];
    const float* qkv_w      = (const float*)d_in[4];
    const float* qkv_b      = (const float*)d_in[5];
    const float* proj_w     = (const float*)d_in[6];
    const float* proj_b     = (const float*)d_in[7];
    const float* rel_bias   = (const float*)d_in[8];
    const float* diff_mu    = (const float*)d_in[9];
    const float* diff_ls    = (const float*)d_in[10];
    const float* ref_qk_w   = (const float*)d_in[11];
    const float* ref_qk_b   = (const float*)d_in[12];
    const float* conv_w     = (const float*)d_in[13];
    const float* conv_b     = (const float*)d_in[14];
    const float* q_norm_w   = (const float*)d_in[15];
    const float* q_norm_b   = (const float*)d_in[16];
    const float* q_proj_w   = (const float*)d_in[17];
    const float* q_proj_b   = (const float*)d_in[18];
    const float* cls_dth_w  = (const float*)d_in[19];
    const float* cls_dth_b  = (const float*)d_in[20];
    const float* cls_seg_w  = (const float*)d_in[21];
    const float* cls_seg_b  = (const float*)d_in[22];
    const float* glob_k_w   = (const float*)d_in[23];
    const float* glob_k_b   = (const float*)d_in[24];
    const float* glob_v_w   = (const float*)d_in[25];
    const float* glob_v_b   = (const float*)d_in[26];
    const float* proj_dth_w = (const float*)d_in[27];
    const float* proj_dth_b = (const float*)d_in[28];

    // ---- workspace layout: total 62.25 MiB ----
    bf16* wsb = (bf16*)d_ws;
    bf16* qkv      = wsb;
    bf16* t_k      = wsb;
    bf16* t_v      = wsb + 9633792;
    bf16* ref_attn = wsb + 19267584;
    bf16* q_new    = ref_attn;
    bf16* depth_q  = ref_attn;
    bf16* seg_q    = ref_attn + 1605632;
    bf16* d_pre    = ref_attn + 3211264;
    bf16* s_pre    = ref_attn + 4816896;
    bf16* u_buf    = wsb + 25690112;
    bf16* ln_t     = u_buf;
    bf16* attn_out = u_buf;
    float* ref_qk  = (float*)((char*)d_ws + 64225280);
    float* ref_q_t = ref_qk + 131072;
    float* ref_v_t = ref_q_t + 65536;
    float* stats   = ref_v_t + 65536;

    float* out0  = (float*)d_out;
    float* out_d = out0 + 6422528;
    float* out_s = out0 + 8028160;

    // 1. qkv = x @ qkv_w + b
    mfma_gemm<<<dim3(12, 392), 256, 0, stream>>>(x, 0, nullptr, nullptr, qkv_w, qkv_b,
                                                 nullptr, 0, nullptr, qkv, 25088, 256, 768, 1.f);
    // 2. ref_qk = x_ref @ ref_qk_w + b
    mfma_gemm<<<dim3(8, 4), 256, 0, stream>>>(x_ref, 0, nullptr, nullptr, ref_qk_w, ref_qk_b,
                                              nullptr, 0, ref_qk, nullptr, 256, 256, 512, 1.f);
    // 3. ref_q_t / ref_v_t
    refprep_kernel<<<256, 256, 0, stream>>>(ref_qk, diff_mu, diff_ls, ref_q_t, ref_v_t);
    // 4. ref_attn scores
    refattn_kernel<<<4096, 256, 0, stream>>>(qkv, ref_q_t, ref_attn);
    // 5. 3x diffusion
    for (int it = 0; it < 3; ++it) {
        conv_kernel<<<392, 256, 0, stream>>>(ref_attn, conv_w, conv_b, u_buf);
        lnstats_kernel<<<64, 256, 0, stream>>>(u_buf, stats);
        lngelu_kernel<<<3136, 256, 0, stream>>>(u_buf, stats, ref_attn);
    }
    // 6. softmax @ ref_v + shortcut + LN -> ln_t
    qnew_pre_kernel<<<6272, 256, 0, stream>>>(qkv, ref_attn, ref_v_t,
                                              q_norm_w, q_norm_b, ln_t);
    // 7. q_new = (ln_t @ q_proj_w + b + qsc) * SCALE
    mfma_gemm<<<dim3(4, 392), 256, 0, stream>>>(ln_t, 1, nullptr, nullptr, q_proj_w, q_proj_b,
                                                qkv, 768, nullptr, q_new, 25088, 256, 256, SCALE_T);
    // 8. window attention
    winattn_kernel<<<4096, 256, 0, stream>>>(qkv, q_new, rel_bias, attn_out);
    // 9. out0 = attn_out @ proj_w + b
    mfma_gemm<<<dim3(4, 392), 256, 0, stream>>>(attn_out, 1, nullptr, nullptr, proj_w, proj_b,
                                                nullptr, 0, out0, nullptr, 25088, 256, 256, 1.f);
    // 10/11. t_k, t_v
    mfma_gemm<<<dim3(6, 392), 256, 0, stream>>>(out0, 2, dth_tok, seg_tok, glob_k_w, glob_k_b,
                                                nullptr, 0, nullptr, t_k, 25088, 384, 384, 1.f);
    mfma_gemm<<<dim3(6, 392), 256, 0, stream>>>(out0, 2, dth_tok, seg_tok, glob_v_w, glob_v_b,
                                                nullptr, 0, nullptr, t_v, 25088, 384, 384, 1.f);
    // 12/13. depth_q, seg_q
    mfma_gemm<<<dim3(1, 392), 256, 0, stream>>>(dth_tok, 0, nullptr, nullptr, cls_dth_w, cls_dth_b,
                                                nullptr, 0, nullptr, depth_q, 25088, 64, 64, SCALE_T);
    mfma_gemm<<<dim3(1, 392), 256, 0, stream>>>(seg_tok, 0, nullptr, nullptr, cls_seg_w, cls_seg_b,
                                                nullptr, 0, nullptr, seg_q, 25088, 64, 64, SCALE_T);
    // 14. class-token attention
    clsattn_kernel<<<4096, 256, 0, stream>>>(t_k, t_v, depth_q, seg_q, d_pre, s_pre);
    // 15/16. final proj_dth
    mfma_gemm<<<dim3(1, 392), 256, 0, stream>>>(d_pre, 1, nullptr, nullptr, proj_dth_w, proj_dth_b,
                                                nullptr, 0, out_d, nullptr, 25088, 64, 64, 1.f);
    mfma_gemm<<<dim3(1, 392), 256, 0, stream>>>(s_pre, 1, nullptr, nullptr, proj_dth_w, proj_dth_b,
                                                nullptr, 0, out_s, nullptr, 25088, 64, 64, 1.f);
}

// Round 7
// 696.968 us; speedup vs baseline: 3.0555x; 1.0076x over previous
//
#include <hip/hip_runtime.h>
#include <hip/hip_bf16.h>

typedef __hip_bfloat16 bf16;
typedef short s16x8 __attribute__((ext_vector_type(8)));
typedef float f32x4 __attribute__((ext_vector_type(4)));
union V16 { uint4 u4; s16x8 s8; unsigned u[4]; };

static __device__ __forceinline__ float b2f(bf16 v){ return __bfloat162float(v); }
static __device__ __forceinline__ bf16  f2b(float v){ return __float2bfloat16(v); }
static __device__ __forceinline__ unsigned short f2bs(float x){
    union { float f; unsigned u; } c; c.f = x;
    unsigned r = c.u + 0x7fff + ((c.u >> 16) & 1);
    return (unsigned short)(r >> 16);
}
static __device__ __forceinline__ float bu2f(unsigned short b){
    union { unsigned u; float f; } c; c.u = ((unsigned)b) << 16; return c.f;
}

#define SCALE_T 0.17677669529663687f   // 32^-0.5

// ---------------------------------------------------------------------------
// MFMA bf16 GEMM: out = (A[M,K] @ W[K,N] + bias [+ add]) * scale
// 64x64 tile, BK=32, 256 threads (4 waves), v_mfma_f32_16x16x32_bf16.
// a_mode: 0 = A f32 [M,K]; 1 = A bf16 [M,K] (ws intermediate);
//         2 = A = concat(A f32[M,256], Xd f32[M,64], Xs f32[M,64]) (K=384)
// ---------------------------------------------------------------------------
__global__ __launch_bounds__(256) void mfma_gemm(
    const void* __restrict__ A, int a_mode,
    const float* __restrict__ Xd, const float* __restrict__ Xs,
    const float* __restrict__ W, const float* __restrict__ bias,
    const bf16* __restrict__ addp, int addStride,
    float* __restrict__ outF, bf16* __restrict__ outB,
    int M, int K, int N, float scale)
{
    __shared__ __hip_bfloat16 Al[64][48];
    __shared__ __hip_bfloat16 Bl[64][48];

    const int tid  = threadIdx.x;
    const int wv   = tid >> 6, lane = tid & 63;
    const int quad = lane >> 4, l15 = lane & 15;
    const int rowBase = blockIdx.y * 64, colBase = blockIdx.x * 64;

    const int am = tid >> 2, ak = (tid & 3) * 8;
    const int bn = tid & 63, bk = (tid >> 6) * 8;

    f32x4 acc[4];
    #pragma unroll
    for (int t = 0; t < 4; ++t)
        #pragma unroll
        for (int r = 0; r < 4; ++r) acc[t][r] = 0.f;

    for (int kt = 0; kt < K; kt += 32) {
        s16x8 sa;
        if (a_mode == 1) {
            const bf16* Ab = (const bf16*)A;
            V16 u; u.u4 = *(const uint4*)(Ab + (size_t)(rowBase + am) * K + kt + ak);
            sa = u.s8;
        } else {
            const float* src; size_t base;
            if (a_mode == 0) {
                src = (const float*)A; base = (size_t)(rowBase + am) * K + kt + ak;
            } else {
                int kcol = kt + ak;
                if (kcol < 256)      { src = (const float*)A; base = (size_t)(rowBase + am) * 256 + kcol; }
                else if (kcol < 320) { src = Xd; base = (size_t)(rowBase + am) * 64 + (kcol - 256); }
                else                 { src = Xs; base = (size_t)(rowBase + am) * 64 + (kcol - 320); }
            }
            const float4* p = (const float4*)(src + base);
            float4 u0 = p[0], u1 = p[1];
            sa[0] = (short)f2bs(u0.x); sa[1] = (short)f2bs(u0.y);
            sa[2] = (short)f2bs(u0.z); sa[3] = (short)f2bs(u0.w);
            sa[4] = (short)f2bs(u1.x); sa[5] = (short)f2bs(u1.y);
            sa[6] = (short)f2bs(u1.z); sa[7] = (short)f2bs(u1.w);
        }
        *(s16x8*)&Al[am][ak] = sa;

        s16x8 sb;
        #pragma unroll
        for (int j = 0; j < 8; ++j)
            sb[j] = (short)f2bs(W[(size_t)(kt + bk + j) * N + colBase + bn]);
        *(s16x8*)&Bl[bn][bk] = sb;

        __syncthreads();

        s16x8 a = *(const s16x8*)&Al[wv * 16 + l15][quad * 8];
        #pragma unroll
        for (int t = 0; t < 4; ++t) {
            s16x8 b = *(const s16x8*)&Bl[t * 16 + l15][quad * 8];
            acc[t] = __builtin_amdgcn_mfma_f32_16x16x32_bf16(a, b, acc[t], 0, 0, 0);
        }
        __syncthreads();
    }

    #pragma unroll
    for (int t = 0; t < 4; ++t) {
        int col = colBase + t * 16 + l15;
        float bb = bias[col];
        #pragma unroll
        for (int r = 0; r < 4; ++r) {
            int row = rowBase + wv * 16 + quad * 4 + r;
            float v = acc[t][r] + bb;
            if (addp) v += b2f(addp[(size_t)row * addStride + col]);
            v *= scale;
            if (outF) outF[(size_t)row * N + col] = v;
            if (outB) outB[(size_t)row * N + col] = f2b(v);
        }
    }
}

// ---------------------------------------------------------------------------
// ref_q_t[r,h,f,d] = mu[c] + exp(ls[c]) * ref_qk[r*32+f, c];  ref_v_t from +256
// ---------------------------------------------------------------------------
__global__ __launch_bounds__(256) void refprep_kernel(
    const float* __restrict__ ref_qk, const float* __restrict__ mu,
    const float* __restrict__ ls, float* __restrict__ ref_q_t,
    float* __restrict__ ref_v_t)
{
    int idx = blockIdx.x * 256 + threadIdx.x;          // [r,h,f,d]
    int d = idx & 31, f = (idx >> 5) & 31, h = (idx >> 10) & 7, r = idx >> 13;
    int c = h * 32 + d;
    size_t src = (size_t)(r * 32 + f) * 512 + c;
    ref_q_t[idx] = mu[c] + __expf(ls[c]) * ref_qk[src];
    ref_v_t[idx] = ref_qk[src + 256];
}

// ---------------------------------------------------------------------------
// ref_attn[r,h,w,n,f] = sum_d (q[b,h,n,d]*SCALE) * ref_q_t[r,h,f,d]
// ---------------------------------------------------------------------------
__global__ __launch_bounds__(256) void refattn_kernel(
    const bf16* __restrict__ qkv, const float* __restrict__ ref_q_t,
    bf16* __restrict__ ref_attn)
{
    int blk = blockIdx.x;
    int w = blk & 63, h = (blk >> 6) & 7, r = blk >> 9;
    int b = r * 64 + w;
    __shared__ float qt[49 * 32];
    __shared__ float rq[32 * 33];
    int tid = threadIdx.x;
    for (int l = tid; l < 1568; l += 256) {
        int n = l >> 5, d = l & 31;
        qt[l] = b2f(qkv[(size_t)(b * 49 + n) * 768 + h * 32 + d]) * SCALE_T;
    }
    for (int l = tid; l < 1024; l += 256) {
        int f = l >> 5, d = l & 31;
        rq[f * 33 + d] = ref_q_t[(size_t)((r * 8 + h) * 32 + f) * 32 + d];
    }
    __syncthreads();
    for (int l = tid; l < 1568; l += 256) {
        int n = l >> 5, f = l & 31;
        float acc = 0.f;
        #pragma unroll
        for (int d2 = 0; d2 < 32; ++d2) acc += qt[n * 32 + d2] * rq[f * 33 + d2];
        ref_attn[(size_t)(((r * 8 + h) * 64 + w) * 49 + n) * 32 + f] = f2b(acc);
    }
}

// ---------------------------------------------------------------------------
// 3x3 SAME conv over [RB=8, 8ch, 3136, 32].
// One thread = all 8 out-channels x 8-wide f vector at one (r,p).
// grid = 392 blocks of 256 (100,352 threads).
// ---------------------------------------------------------------------------
__global__ __launch_bounds__(256) void conv_kernel(
    const bf16* __restrict__ in, const float* __restrict__ conv_w,
    const float* __restrict__ conv_b, bf16* __restrict__ u)
{
    __shared__ float w_s[576];
    __shared__ float b_s[8];
    int tid = threadIdx.x;
    for (int l = tid; l < 576; l += 256) w_s[l] = conv_w[l];
    if (tid < 8) b_s[tid] = conv_b[tid];
    __syncthreads();

    int idx = blockIdx.x * 256 + tid;          // < 100352
    int fb = idx & 3;
    int p  = (idx >> 2) % 3136;
    int r  = idx / 12544;
    int f0 = fb * 8;

    float acc[8][8];
    #pragma unroll
    for (int o = 0; o < 8; ++o) {
        float bo = b_s[o];
        #pragma unroll
        for (int f = 0; f < 8; ++f) acc[o][f] = bo;
    }

    for (int i = 0; i < 8; ++i) {
        float ext[3][10];
        #pragma unroll
        for (int dy = 0; dy < 3; ++dy) {
            int pp = p + dy - 1;
            bool pv = (unsigned)pp < 3136u;
            size_t base = ((size_t)((r * 8 + i) * 3136 + (pv ? pp : 0))) * 32 + f0;
            V16 uv;
            uv.u4 = pv ? *(const uint4*)(in + base) : make_uint4(0, 0, 0, 0);
            #pragma unroll
            for (int j = 0; j < 8; ++j) {
                unsigned sh = uv.u[j >> 1];
                unsigned bits = (j & 1) ? (sh & 0xffff0000u) : (sh << 16);
                union { unsigned uu; float fl; } cv; cv.uu = bits;
                ext[dy][j + 1] = cv.fl;
            }
            ext[dy][0] = (pv && f0 > 0)      ? b2f(in[base - 1]) : 0.f;
            ext[dy][9] = (pv && f0 + 8 < 32) ? b2f(in[base + 8]) : 0.f;
        }
        #pragma unroll
        for (int o = 0; o < 8; ++o) {
            #pragma unroll
            for (int ky = 0; ky < 3; ++ky) {
                const float* wp = &w_s[((o * 8 + i) * 3 + ky) * 3];
                float w0 = wp[0], w1 = wp[1], w2 = wp[2];
                #pragma unroll
                for (int f = 0; f < 8; ++f)
                    acc[o][f] += ext[ky][f] * w0 + ext[ky][f + 1] * w1 + ext[ky][f + 2] * w2;
            }
        }
    }

    #pragma unroll
    for (int o = 0; o < 8; ++o) {
        bf16 ov[8];
        #pragma unroll
        for (int f = 0; f < 8; ++f) ov[f] = f2b(acc[o][f]);
        *(uint4*)(u + ((size_t)((r * 8 + o) * 3136 + p)) * 32 + f0) = *(uint4*)ov;
    }
}

// ---------------------------------------------------------------------------
// Per-(r,ch) mean/rstd over contiguous 100352-elem map.  64 blocks, bf16x8.
// ---------------------------------------------------------------------------
__global__ __launch_bounds__(256) void lnstats_kernel(
    const bf16* __restrict__ u, float* __restrict__ stats)
{
    int g = blockIdx.x;
    const bf16* p = u + (size_t)g * 100352;
    int tid = threadIdx.x;
    float s = 0.f, s2 = 0.f;
    for (int it = tid; it < 12544; it += 256) {
        V16 uv; uv.u4 = *(const uint4*)(p + it * 8);
        #pragma unroll
        for (int j = 0; j < 8; ++j) {
            unsigned sh = uv.u[j >> 1];
            unsigned bits = (j & 1) ? (sh & 0xffff0000u) : (sh << 16);
            union { unsigned uu; float fl; } cv; cv.uu = bits;
            s += cv.fl; s2 += cv.fl * cv.fl;
        }
    }
    __shared__ float r1[256], r2[256];
    r1[tid] = s; r2[tid] = s2; __syncthreads();
    for (int st = 128; st > 0; st >>= 1) {
        if (tid < st) { r1[tid] += r1[tid + st]; r2[tid] += r2[tid + st]; }
        __syncthreads();
    }
    if (tid == 0) {
        float mean = r1[0] * (1.f / 100352.f);
        float var  = r2[0] * (1.f / 100352.f) - mean * mean;
        var = fmaxf(var, 0.f);
        stats[g * 2] = mean;
        stats[g * 2 + 1] = rsqrtf(var + 1e-5f);
    }
}

// ref_attn += gelu_exact( (u - mean) * rstd );  bf16x8, grid = 3136 blocks.
__global__ __launch_bounds__(256) void lngelu_kernel(
    const bf16* __restrict__ u, const float* __restrict__ stats,
    bf16* __restrict__ ref_attn)
{
    int idx8 = blockIdx.x * 256 + threadIdx.x;    // < 802816
    int g = idx8 / 12544;
    size_t base = (size_t)idx8 * 8;
    float mean = stats[g * 2], rstd = stats[g * 2 + 1];
    V16 uv; uv.u4 = *(const uint4*)(u + base);
    V16 rv; rv.u4 = *(const uint4*)(ref_attn + base);
    bf16 outv[8];
    #pragma unroll
    for (int j = 0; j < 8; ++j) {
        unsigned shu = uv.u[j >> 1];
        unsigned shr = rv.u[j >> 1];
        unsigned bu = (j & 1) ? (shu & 0xffff0000u) : (shu << 16);
        unsigned br = (j & 1) ? (shr & 0xffff0000u) : (shr << 16);
        union { unsigned uu; float fl; } cu, cr; cu.uu = bu; cr.uu = br;
        float v = (cu.fl - mean) * rstd;
        float ge = 0.5f * v * (1.f + erff(v * 0.7071067811865476f));
        outv[j] = f2b(cr.fl + ge);
    }
    *(uint4*)(ref_attn + base) = *(uint4*)outv;
}

// ---------------------------------------------------------------------------
// qnew_pre: per row (b,n): softmax(32)@ref_v + q_sc, LN(256) -> ln_t (bf16).
// One WAVE per row, no LDS, no barriers.  grid = 6272 blocks of 256 (4 rows).
// ---------------------------------------------------------------------------
__global__ __launch_bounds__(256) void qnew_pre_kernel(
    const bf16* __restrict__ qkv, const bf16* __restrict__ ref_attn,
    const float* __restrict__ ref_v_t,
    const float* __restrict__ qnw, const float* __restrict__ qnb,
    bf16* __restrict__ ln_t)
{
    int ww = threadIdx.x >> 6, lane = threadIdx.x & 63;
    int row = blockIdx.x * 4 + ww;            // < 25088
    int b = row / 49, n = row % 49;
    int r = b >> 6, w = b & 63;
    int h = lane >> 3, d0 = (lane & 7) * 4;

    const bf16* la = ref_attn + ((size_t)(((r * 8 + h) * 64 + w) * 49 + n)) * 32 + d0;
    ushort4 lu = *(const ushort4*)la;
    float lg[4] = { bu2f(lu.x), bu2f(lu.y), bu2f(lu.z), bu2f(lu.w) };

    float m = fmaxf(fmaxf(lg[0], lg[1]), fmaxf(lg[2], lg[3]));
    m = fmaxf(m, __shfl_xor(m, 1));
    m = fmaxf(m, __shfl_xor(m, 2));
    m = fmaxf(m, __shfl_xor(m, 4));
    float p[4], s = 0.f;
    #pragma unroll
    for (int j = 0; j < 4; ++j) { p[j] = __expf(lg[j] - m); s += p[j]; }
    s += __shfl_xor(s, 1);
    s += __shfl_xor(s, 2);
    s += __shfl_xor(s, 4);
    float inv = 1.f / s;
    #pragma unroll
    for (int j = 0; j < 4; ++j) p[j] *= inv;

    const float* rv = ref_v_t + ((size_t)(r * 8 + h) * 32) * 32 + d0;
    float y[4] = {0.f, 0.f, 0.f, 0.f};
    #pragma unroll
    for (int f = 0; f < 32; ++f) {
        int src = (lane & 56) | (f >> 2);
        float pf = __shfl(p[f & 3], src);
        float4 rvf = *(const float4*)(rv + f * 32);
        y[0] += pf * rvf.x; y[1] += pf * rvf.y;
        y[2] += pf * rvf.z; y[3] += pf * rvf.w;
    }

    ushort4 qu = *(const ushort4*)(qkv + (size_t)row * 768 + lane * 4);
    float z[4] = { y[0] + bu2f(qu.x), y[1] + bu2f(qu.y),
                   y[2] + bu2f(qu.z), y[3] + bu2f(qu.w) };

    float s1 = z[0] + z[1] + z[2] + z[3];
    #pragma unroll
    for (int off = 1; off < 64; off <<= 1) s1 += __shfl_xor(s1, off);
    float mean = s1 * (1.f / 256.f);
    float zc[4] = { z[0] - mean, z[1] - mean, z[2] - mean, z[3] - mean };
    float s2 = zc[0]*zc[0] + zc[1]*zc[1] + zc[2]*zc[2] + zc[3]*zc[3];
    #pragma unroll
    for (int off = 1; off < 64; off <<= 1) s2 += __shfl_xor(s2, off);
    float rstd = rsqrtf(s2 * (1.f / 256.f) + 1e-5f);

    float4 wv = *(const float4*)(qnw + lane * 4);
    float4 bv = *(const float4*)(qnb + lane * 4);
    bf16 outv[4];
    outv[0] = f2b(zc[0] * rstd * wv.x + bv.x);
    outv[1] = f2b(zc[1] * rstd * wv.y + bv.y);
    outv[2] = f2b(zc[2] * rstd * wv.z + bv.z);
    outv[3] = f2b(zc[3] * rstd * wv.w + bv.w);
    *(ushort4*)(ln_t + (size_t)row * 256 + lane * 4) = *(ushort4*)outv;
}

// ---------------------------------------------------------------------------
// Window attention per (b,h): softmax(q_new k^T + bias) @ v.  4096 blocks.
// LDS layout: qn/kk rows padded to 33 (QK bank = (m+d2)%32, conflict-free);
// vv stride 32 (float4 PV reads, banks covered 2x/wave = free); sc stride 50.
// ---------------------------------------------------------------------------
__global__ __launch_bounds__(256) void winattn_kernel(
    const bf16* __restrict__ qkv, const bf16* __restrict__ q_new,
    const float* __restrict__ rel_bias, bf16* __restrict__ attn_out)
{
    int bh = blockIdx.x;
    int b = bh >> 3, h = bh & 7;
    int tid = threadIdx.x;
    int wv = tid >> 6, lane = tid & 63;
    __shared__ float qn[49 * 33], kk[49 * 33], vv[49 * 32], sc[49 * 50];

    // staging: ushort4 (4 d's) per thread-iter
    for (int l = tid; l < 392; l += 256) {
        int n = l >> 3, d0 = (l & 7) * 4;
        size_t rq = (size_t)(b * 49 + n);
        ushort4 qu = *(const ushort4*)(q_new + rq * 256 + h * 32 + d0);
        ushort4 ku = *(const ushort4*)(qkv + rq * 768 + 256 + h * 32 + d0);
        ushort4 vu = *(const ushort4*)(qkv + rq * 768 + 512 + h * 32 + d0);
        qn[n * 33 + d0 + 0] = bu2f(qu.x); qn[n * 33 + d0 + 1] = bu2f(qu.y);
        qn[n * 33 + d0 + 2] = bu2f(qu.z); qn[n * 33 + d0 + 3] = bu2f(qu.w);
        kk[n * 33 + d0 + 0] = bu2f(ku.x); kk[n * 33 + d0 + 1] = bu2f(ku.y);
        kk[n * 33 + d0 + 2] = bu2f(ku.z); kk[n * 33 + d0 + 3] = bu2f(ku.w);
        float4 vf = { bu2f(vu.x), bu2f(vu.y), bu2f(vu.z), bu2f(vu.w) };
        *(float4*)&vv[n * 32 + d0] = vf;
    }
    __syncthreads();

    // QK^T + bias
    for (int l = tid; l < 2401; l += 256) {
        int n = l / 49, m = l % 49;
        float acc = 0.f;
        #pragma unroll
        for (int d2 = 0; d2 < 32; ++d2) acc += qn[n * 33 + d2] * kk[m * 33 + d2];
        int ni = n / 7, nj = n % 7, mi = m / 7, mj = m % 7;
        int bidx = ((ni - mi + 6) * 13 + (nj - mj + 6)) * 8 + h;
        sc[n * 50 + m] = acc + rel_bias[bidx];
    }
    __syncthreads();

    // softmax: one wave-row per n, shuffle reductions
    for (int n = wv; n < 49; n += 4) {
        float v = (lane < 49) ? sc[n * 50 + lane] : -1e30f;
        float mx = v;
        #pragma unroll
        for (int off = 1; off < 64; off <<= 1) mx = fmaxf(mx, __shfl_xor(mx, off));
        float e = (lane < 49) ? __expf(v - mx) : 0.f;
        float s = e;
        #pragma unroll
        for (int off = 1; off < 64; off <<= 1) s += __shfl_xor(s, off);
        if (lane < 49) sc[n * 50 + lane] = e / s;
    }
    __syncthreads();

    // P @ V : one thread = 4 outputs (float4 vv reads)
    for (int l = tid; l < 392; l += 256) {
        int n = l >> 3, d0 = (l & 7) * 4;
        float a0 = 0.f, a1 = 0.f, a2 = 0.f, a3 = 0.f;
        for (int m = 0; m < 49; ++m) {
            float pf = sc[n * 50 + m];
            float4 vf = *(const float4*)&vv[m * 32 + d0];
            a0 += pf * vf.x; a1 += pf * vf.y; a2 += pf * vf.z; a3 += pf * vf.w;
        }
        ushort4 ov = { f2bs(a0), f2bs(a1), f2bs(a2), f2bs(a3) };
        *(ushort4*)(attn_out + ((size_t)(b * 49 + n)) * 256 + h * 32 + d0) = ov;
    }
}

// ---------------------------------------------------------------------------
// Class-token attention per (b,h): both depth & seg.  4096 blocks.
// ---------------------------------------------------------------------------
__global__ __launch_bounds__(256) void clsattn_kernel(
    const bf16* __restrict__ t_k, const bf16* __restrict__ t_v,
    const bf16* __restrict__ depth_q, const bf16* __restrict__ seg_q,
    bf16* __restrict__ d_pre, bf16* __restrict__ s_pre)
{
    int bh = blockIdx.x;
    int b = bh >> 3, h = bh & 7;
    int tid = threadIdx.x;
    __shared__ float tk[2352], tv[2352], dq[392], sq[392], pl[2][384];
    for (int l = tid; l < 2352; l += 256) {
        int n = l / 48, t = l % 48;
        size_t row = (size_t)(b * 49 + n);
        tk[l] = b2f(t_k[row * 384 + h * 48 + t]);
        tv[l] = b2f(t_v[row * 384 + h * 48 + t]);
    }
    for (int l = tid; l < 392; l += 256) {
        int n = l / 8, c = l % 8;
        size_t row = (size_t)(b * 49 + n);
        dq[l] = b2f(depth_q[row * 64 + h * 8 + c]);
        sq[l] = b2f(seg_q[row * 64 + h * 8 + c]);
    }
    __syncthreads();
    for (int l = tid; l < 768; l += 256) {
        int which = l / 384, cc = (l % 384) / 48, t = l % 48;
        const float* q = which ? sq : dq;
        float acc = 0.f;
        for (int n = 0; n < 49; ++n) acc += q[n * 8 + cc] * tk[n * 48 + t];
        pl[which][cc * 48 + t] = acc;
    }
    __syncthreads();
    if (tid < 16) {
        int which = tid >> 3, cc = tid & 7;
        float* p = &pl[which][cc * 48];
        float mx = -1e30f;
        for (int t = 0; t < 48; ++t) mx = fmaxf(mx, p[t]);
        float s = 0.f;
        for (int t = 0; t < 48; ++t) { float e = __expf(p[t] - mx); p[t] = e; s += e; }
        float inv = 1.f / s;
        for (int t = 0; t < 48; ++t) p[t] *= inv;
    }
    __syncthreads();
    for (int l = tid; l < 784; l += 256) {
        int which = l / 392, cc = (l % 392) / 49, n = l % 49;
        const float* p = &pl[which][cc * 48];
        float acc = 0.f;
        for (int t = 0; t < 48; ++t) acc += p[t] * tv[n * 48 + t];
        bf16* outp = which ? s_pre : d_pre;
        outp[(size_t)(b * 49 + n) * 64 + h * 8 + cc] = f2b(acc);
    }
}

// ---------------------------------------------------------------------------
extern "C" void kernel_launch(void* const* d_in, const int* in_sizes, int n_in,
                              void* d_out, int out_size, void* d_ws, size_t ws_size,
                              hipStream_t stream)
{
    const float* x          = (const float*)d_in[0];
    const float* x_ref      = (const float*)d_in[1];
    const float* dth_tok    = (const float*)d_in[2];
    const float* seg_tok    = (const float*)d_in[3];
    const float* qkv_w      = (const float*)d_in[4];
    const float* qkv_b      = (const float*)d_in[5];
    const float* proj_w     = (const float*)d_in[6];
    const float* proj_b     = (const float*)d_in[7];
    const float* rel_bias   = (const float*)d_in[8];
    const float* diff_mu    = (const float*)d_in[9];
    const float* diff_ls    = (const float*)d_in[10];
    const float* ref_qk_w   = (const float*)d_in[11];
    const float* ref_qk_b   = (const float*)d_in[12];
    const float* conv_w     = (const float*)d_in[13];
    const float* conv_b     = (const float*)d_in[14];
    const float* q_norm_w   = (const float*)d_in[15];
    const float* q_norm_b   = (const float*)d_in[16];
    const float* q_proj_w   = (const float*)d_in[17];
    const float* q_proj_b   = (const float*)d_in[18];
    const float* cls_dth_w  = (const float*)d_in[19];
    const float* cls_dth_b  = (const float*)d_in[20];
    const float* cls_seg_w  = (const float*)d_in[21];
    const float* cls_seg_b  = (const float*)d_in[22];
    const float* glob_k_w   = (const float*)d_in[23];
    const float* glob_k_b   = (const float*)d_in[24];
    const float* glob_v_w   = (const float*)d_in[25];
    const float* glob_v_b   = (const float*)d_in[26];
    const float* proj_dth_w = (const float*)d_in[27];
    const float* proj_dth_b = (const float*)d_in[28];

    // ---- workspace layout: total 62.25 MiB ----
    bf16* wsb = (bf16*)d_ws;
    bf16* qkv      = wsb;
    bf16* t_k      = wsb;
    bf16* t_v      = wsb + 9633792;
    bf16* ref_attn = wsb + 19267584;
    bf16* q_new    = ref_attn;
    bf16* depth_q  = ref_attn;
    bf16* seg_q    = ref_attn + 1605632;
    bf16* d_pre    = ref_attn + 3211264;
    bf16* s_pre    = ref_attn + 4816896;
    bf16* u_buf    = wsb + 25690112;
    bf16* ln_t     = u_buf;
    bf16* attn_out = u_buf;
    float* ref_qk  = (float*)((char*)d_ws + 64225280);
    float* ref_q_t = ref_qk + 131072;
    float* ref_v_t = ref_q_t + 65536;
    float* stats   = ref_v_t + 65536;

    float* out0  = (float*)d_out;
    float* out_d = out0 + 6422528;
    float* out_s = out0 + 8028160;

    // 1. qkv = x @ qkv_w + b
    mfma_gemm<<<dim3(12, 392), 256, 0, stream>>>(x, 0, nullptr, nullptr, qkv_w, qkv_b,
                                                 nullptr, 0, nullptr, qkv, 25088, 256, 768, 1.f);
    // 2. ref_qk = x_ref @ ref_qk_w + b
    mfma_gemm<<<dim3(8, 4), 256, 0, stream>>>(x_ref, 0, nullptr, nullptr, ref_qk_w, ref_qk_b,
                                              nullptr, 0, ref_qk, nullptr, 256, 256, 512, 1.f);
    // 3. ref_q_t / ref_v_t
    refprep_kernel<<<256, 256, 0, stream>>>(ref_qk, diff_mu, diff_ls, ref_q_t, ref_v_t);
    // 4. ref_attn scores
    refattn_kernel<<<4096, 256, 0, stream>>>(qkv, ref_q_t, ref_attn);
    // 5. 3x diffusion
    for (int it = 0; it < 3; ++it) {
        conv_kernel<<<392, 256, 0, stream>>>(ref_attn, conv_w, conv_b, u_buf);
        lnstats_kernel<<<64, 256, 0, stream>>>(u_buf, stats);
        lngelu_kernel<<<3136, 256, 0, stream>>>(u_buf, stats, ref_attn);
    }
    // 6. softmax @ ref_v + shortcut + LN -> ln_t
    qnew_pre_kernel<<<6272, 256, 0, stream>>>(qkv, ref_attn, ref_v_t,
                                              q_norm_w, q_norm_b, ln_t);
    // 7. q_new = (ln_t @ q_proj_w + b + qsc) * SCALE
    mfma_gemm<<<dim3(4, 392), 256, 0, stream>>>(ln_t, 1, nullptr, nullptr, q_proj_w, q_proj_b,
                                                qkv, 768, nullptr, q_new, 25088, 256, 256, SCALE_T);
    // 8. window attention
    winattn_kernel<<<4096, 256, 0, stream>>>(qkv, q_new, rel_bias, attn_out);
    // 9. out0 = attn_out @ proj_w + b
    mfma_gemm<<<dim3(4, 392), 256, 0, stream>>>(attn_out, 1, nullptr, nullptr, proj_w, proj_b,
                                                nullptr, 0, out0, nullptr, 25088, 256, 256, 1.f);
    // 10/11. t_k, t_v
    mfma_gemm<<<dim3(6, 392), 256, 0, stream>>>(out0, 2, dth_tok, seg_tok, glob_k_w, glob_k_b,
                                                nullptr, 0, nullptr, t_k, 25088, 384, 384, 1.f);
    mfma_gemm<<<dim3(6, 392), 256, 0, stream>>>(out0, 2, dth_tok, seg_tok, glob_v_w, glob_v_b,
                                                nullptr, 0, nullptr, t_v, 25088, 384, 384, 1.f);
    // 12/13. depth_q, seg_q
    mfma_gemm<<<dim3(1, 392), 256, 0, stream>>>(dth_tok, 0, nullptr, nullptr, cls_dth_w, cls_dth_b,
                                                nullptr, 0, nullptr, depth_q, 25088, 64, 64, SCALE_T);
    mfma_gemm<<<dim3(1, 392), 256, 0, stream>>>(seg_tok, 0, nullptr, nullptr, cls_seg_w, cls_seg_b,
                                                nullptr, 0, nullptr, seg_q, 25088, 64, 64, SCALE_T);
    // 14. class-token attention
    clsattn_kernel<<<4096, 256, 0, stream>>>(t_k, t_v, depth_q, seg_q, d_pre, s_pre);
    // 15/16. final proj_dth
    mfma_gemm<<<dim3(1, 392), 256, 0, stream>>>(d_pre, 1, nullptr, nullptr, proj_dth_w, proj_dth_b,
                                                nullptr, 0, out_d, nullptr, 25088, 64, 64, 1.f);
    mfma_gemm<<<dim3(1, 392), 256, 0, stream>>>(s_pre, 1, nullptr, nullptr, proj_dth_w, proj_dth_b,
                                                nullptr, 0, out_s, nullptr, 25088, 64, 64, 1.f);
}

// Round 8
// 633.159 us; speedup vs baseline: 3.3634x; 1.1008x over previous
//
#include <hip/hip_runtime.h>
#include <hip/hip_bf16.h>

typedef __hip_bfloat16 bf16;
typedef short s16x8 __attribute__((ext_vector_type(8)));
typedef float f32x4 __attribute__((ext_vector_type(4)));
union V16 { uint4 u4; s16x8 s8; unsigned u[4]; unsigned short s[8]; };

static __device__ __forceinline__ float b2f(bf16 v){ return __bfloat162float(v); }
static __device__ __forceinline__ bf16  f2b(float v){ return __float2bfloat16(v); }
static __device__ __forceinline__ unsigned short f2bs(float x){
    union { float f; unsigned u; } c; c.f = x;
    unsigned r = c.u + 0x7fff + ((c.u >> 16) & 1);
    return (unsigned short)(r >> 16);
}
static __device__ __forceinline__ float bu2f(unsigned short b){
    union { unsigned u; float f; } c; c.u = ((unsigned)b) << 16; return c.f;
}
static __device__ __forceinline__ s16x8 ld16g(const bf16* p){
    V16 u; u.u4 = *(const uint4*)p; return u.s8;
}

#define SCALE_T 0.17677669529663687f   // 32^-0.5

// ---------------------------------------------------------------------------
// MFMA bf16 GEMM: out = (A[M,K] @ W[K,N] + bias [+ add]) * scale
// 64x64 tile, BK=32, 256 threads (4 waves), v_mfma_f32_16x16x32_bf16.
// a_mode: 0 = A f32 [M,K]; 1 = A bf16 [M,K] (ws intermediate);
//         2 = A = concat(A f32[M,256], Xd f32[M,64], Xs f32[M,64]) (K=384)
// ---------------------------------------------------------------------------
__global__ __launch_bounds__(256) void mfma_gemm(
    const void* __restrict__ A, int a_mode,
    const float* __restrict__ Xd, const float* __restrict__ Xs,
    const float* __restrict__ W, const float* __restrict__ bias,
    const bf16* __restrict__ addp, int addStride,
    float* __restrict__ outF, bf16* __restrict__ outB,
    int M, int K, int N, float scale)
{
    __shared__ __hip_bfloat16 Al[64][48];
    __shared__ __hip_bfloat16 Bl[64][48];

    const int tid  = threadIdx.x;
    const int wv   = tid >> 6, lane = tid & 63;
    const int quad = lane >> 4, l15 = lane & 15;
    const int rowBase = blockIdx.y * 64, colBase = blockIdx.x * 64;

    const int am = tid >> 2, ak = (tid & 3) * 8;
    const int bn = tid & 63, bk = (tid >> 6) * 8;

    f32x4 acc[4];
    #pragma unroll
    for (int t = 0; t < 4; ++t)
        #pragma unroll
        for (int r = 0; r < 4; ++r) acc[t][r] = 0.f;

    for (int kt = 0; kt < K; kt += 32) {
        s16x8 sa;
        if (a_mode == 1) {
            const bf16* Ab = (const bf16*)A;
            V16 u; u.u4 = *(const uint4*)(Ab + (size_t)(rowBase + am) * K + kt + ak);
            sa = u.s8;
        } else {
            const float* src; size_t base;
            if (a_mode == 0) {
                src = (const float*)A; base = (size_t)(rowBase + am) * K + kt + ak;
            } else {
                int kcol = kt + ak;
                if (kcol < 256)      { src = (const float*)A; base = (size_t)(rowBase + am) * 256 + kcol; }
                else if (kcol < 320) { src = Xd; base = (size_t)(rowBase + am) * 64 + (kcol - 256); }
                else                 { src = Xs; base = (size_t)(rowBase + am) * 64 + (kcol - 320); }
            }
            const float4* p = (const float4*)(src + base);
            float4 u0 = p[0], u1 = p[1];
            sa[0] = (short)f2bs(u0.x); sa[1] = (short)f2bs(u0.y);
            sa[2] = (short)f2bs(u0.z); sa[3] = (short)f2bs(u0.w);
            sa[4] = (short)f2bs(u1.x); sa[5] = (short)f2bs(u1.y);
            sa[6] = (short)f2bs(u1.z); sa[7] = (short)f2bs(u1.w);
        }
        *(s16x8*)&Al[am][ak] = sa;

        s16x8 sb;
        #pragma unroll
        for (int j = 0; j < 8; ++j)
            sb[j] = (short)f2bs(W[(size_t)(kt + bk + j) * N + colBase + bn]);
        *(s16x8*)&Bl[bn][bk] = sb;

        __syncthreads();

        s16x8 a = *(const s16x8*)&Al[wv * 16 + l15][quad * 8];
        #pragma unroll
        for (int t = 0; t < 4; ++t) {
            s16x8 b = *(const s16x8*)&Bl[t * 16 + l15][quad * 8];
            acc[t] = __builtin_amdgcn_mfma_f32_16x16x32_bf16(a, b, acc[t], 0, 0, 0);
        }
        __syncthreads();
    }

    #pragma unroll
    for (int t = 0; t < 4; ++t) {
        int col = colBase + t * 16 + l15;
        float bb = bias[col];
        #pragma unroll
        for (int r = 0; r < 4; ++r) {
            int row = rowBase + wv * 16 + quad * 4 + r;
            float v = acc[t][r] + bb;
            if (addp) v += b2f(addp[(size_t)row * addStride + col]);
            v *= scale;
            if (outF) outF[(size_t)row * N + col] = v;
            if (outB) outB[(size_t)row * N + col] = f2b(v);
        }
    }
}

// ---------------------------------------------------------------------------
// ref_q_t[r,h,f,d] = mu[c] + exp(ls[c]) * ref_qk[r*32+f, c];  ref_v_t from +256
// ---------------------------------------------------------------------------
__global__ __launch_bounds__(256) void refprep_kernel(
    const float* __restrict__ ref_qk, const float* __restrict__ mu,
    const float* __restrict__ ls, float* __restrict__ ref_q_t,
    float* __restrict__ ref_v_t)
{
    int idx = blockIdx.x * 256 + threadIdx.x;          // [r,h,f,d]
    int d = idx & 31, f = (idx >> 5) & 31, h = (idx >> 10) & 7, r = idx >> 13;
    int c = h * 32 + d;
    size_t src = (size_t)(r * 32 + f) * 512 + c;
    ref_q_t[idx] = mu[c] + __expf(ls[c]) * ref_qk[src];
    ref_v_t[idx] = ref_qk[src + 256];
}

// ---------------------------------------------------------------------------
// ref_attn[r,h,w,n,f] = sum_d (q[b,h,n,d]*SCALE) * ref_q_t[r,h,f,d]
// ---------------------------------------------------------------------------
__global__ __launch_bounds__(256) void refattn_kernel(
    const bf16* __restrict__ qkv, const float* __restrict__ ref_q_t,
    bf16* __restrict__ ref_attn)
{
    int blk = blockIdx.x;
    int w = blk & 63, h = (blk >> 6) & 7, r = blk >> 9;
    int b = r * 64 + w;
    __shared__ float qt[49 * 32];
    __shared__ float rq[32 * 33];
    int tid = threadIdx.x;
    for (int l = tid; l < 1568; l += 256) {
        int n = l >> 5, d = l & 31;
        qt[l] = b2f(qkv[(size_t)(b * 49 + n) * 768 + h * 32 + d]) * SCALE_T;
    }
    for (int l = tid; l < 1024; l += 256) {
        int f = l >> 5, d = l & 31;
        rq[f * 33 + d] = ref_q_t[(size_t)((r * 8 + h) * 32 + f) * 32 + d];
    }
    __syncthreads();
    for (int l = tid; l < 1568; l += 256) {
        int n = l >> 5, f = l & 31;
        float acc = 0.f;
        #pragma unroll
        for (int d2 = 0; d2 < 32; ++d2) acc += qt[n * 32 + d2] * rq[f * 33 + d2];
        ref_attn[(size_t)(((r * 8 + h) * 64 + w) * 49 + n) * 32 + f] = f2b(acc);
    }
}

// ---------------------------------------------------------------------------
// 3x3 SAME conv over [RB=8, 8ch, 3136, 32].
// ---------------------------------------------------------------------------
__global__ __launch_bounds__(256) void conv_kernel(
    const bf16* __restrict__ in, const float* __restrict__ conv_w,
    const float* __restrict__ conv_b, bf16* __restrict__ u)
{
    __shared__ float w_s[576];
    __shared__ float b_s[8];
    int tid = threadIdx.x;
    for (int l = tid; l < 576; l += 256) w_s[l] = conv_w[l];
    if (tid < 8) b_s[tid] = conv_b[tid];
    __syncthreads();

    int idx = blockIdx.x * 256 + tid;          // < 100352
    int fb = idx & 3;
    int p  = (idx >> 2) % 3136;
    int r  = idx / 12544;
    int f0 = fb * 8;

    float acc[8][8];
    #pragma unroll
    for (int o = 0; o < 8; ++o) {
        float bo = b_s[o];
        #pragma unroll
        for (int f = 0; f < 8; ++f) acc[o][f] = bo;
    }

    for (int i = 0; i < 8; ++i) {
        float ext[3][10];
        #pragma unroll
        for (int dy = 0; dy < 3; ++dy) {
            int pp = p + dy - 1;
            bool pv = (unsigned)pp < 3136u;
            size_t base = ((size_t)((r * 8 + i) * 3136 + (pv ? pp : 0))) * 32 + f0;
            V16 uv;
            uv.u4 = pv ? *(const uint4*)(in + base) : make_uint4(0, 0, 0, 0);
            #pragma unroll
            for (int j = 0; j < 8; ++j) {
                unsigned sh = uv.u[j >> 1];
                unsigned bits = (j & 1) ? (sh & 0xffff0000u) : (sh << 16);
                union { unsigned uu; float fl; } cv; cv.uu = bits;
                ext[dy][j + 1] = cv.fl;
            }
            ext[dy][0] = (pv && f0 > 0)      ? b2f(in[base - 1]) : 0.f;
            ext[dy][9] = (pv && f0 + 8 < 32) ? b2f(in[base + 8]) : 0.f;
        }
        #pragma unroll
        for (int o = 0; o < 8; ++o) {
            #pragma unroll
            for (int ky = 0; ky < 3; ++ky) {
                const float* wp = &w_s[((o * 8 + i) * 3 + ky) * 3];
                float w0 = wp[0], w1 = wp[1], w2 = wp[2];
                #pragma unroll
                for (int f = 0; f < 8; ++f)
                    acc[o][f] += ext[ky][f] * w0 + ext[ky][f + 1] * w1 + ext[ky][f + 2] * w2;
            }
        }
    }

    #pragma unroll
    for (int o = 0; o < 8; ++o) {
        bf16 ov[8];
        #pragma unroll
        for (int f = 0; f < 8; ++f) ov[f] = f2b(acc[o][f]);
        *(uint4*)(u + ((size_t)((r * 8 + o) * 3136 + p)) * 32 + f0) = *(uint4*)ov;
    }
}

// ---------------------------------------------------------------------------
// Per-(r,ch) mean/rstd over contiguous 100352-elem map.  64 blocks, bf16x8.
// ---------------------------------------------------------------------------
__global__ __launch_bounds__(256) void lnstats_kernel(
    const bf16* __restrict__ u, float* __restrict__ stats)
{
    int g = blockIdx.x;
    const bf16* p = u + (size_t)g * 100352;
    int tid = threadIdx.x;
    float s = 0.f, s2 = 0.f;
    for (int it = tid; it < 12544; it += 256) {
        V16 uv; uv.u4 = *(const uint4*)(p + it * 8);
        #pragma unroll
        for (int j = 0; j < 8; ++j) {
            unsigned sh = uv.u[j >> 1];
            unsigned bits = (j & 1) ? (sh & 0xffff0000u) : (sh << 16);
            union { unsigned uu; float fl; } cv; cv.uu = bits;
            s += cv.fl; s2 += cv.fl * cv.fl;
        }
    }
    __shared__ float r1[256], r2[256];
    r1[tid] = s; r2[tid] = s2; __syncthreads();
    for (int st = 128; st > 0; st >>= 1) {
        if (tid < st) { r1[tid] += r1[tid + st]; r2[tid] += r2[tid + st]; }
        __syncthreads();
    }
    if (tid == 0) {
        float mean = r1[0] * (1.f / 100352.f);
        float var  = r2[0] * (1.f / 100352.f) - mean * mean;
        var = fmaxf(var, 0.f);
        stats[g * 2] = mean;
        stats[g * 2 + 1] = rsqrtf(var + 1e-5f);
    }
}

// ref_attn += gelu_exact( (u - mean) * rstd );  bf16x8, grid = 3136 blocks.
__global__ __launch_bounds__(256) void lngelu_kernel(
    const bf16* __restrict__ u, const float* __restrict__ stats,
    bf16* __restrict__ ref_attn)
{
    int idx8 = blockIdx.x * 256 + threadIdx.x;    // < 802816
    int g = idx8 / 12544;
    size_t base = (size_t)idx8 * 8;
    float mean = stats[g * 2], rstd = stats[g * 2 + 1];
    V16 uv; uv.u4 = *(const uint4*)(u + base);
    V16 rv; rv.u4 = *(const uint4*)(ref_attn + base);
    bf16 outv[8];
    #pragma unroll
    for (int j = 0; j < 8; ++j) {
        unsigned shu = uv.u[j >> 1];
        unsigned shr = rv.u[j >> 1];
        unsigned bu = (j & 1) ? (shu & 0xffff0000u) : (shu << 16);
        unsigned br = (j & 1) ? (shr & 0xffff0000u) : (shr << 16);
        union { unsigned uu; float fl; } cu, cr; cu.uu = bu; cr.uu = br;
        float v = (cu.fl - mean) * rstd;
        float ge = 0.5f * v * (1.f + erff(v * 0.7071067811865476f));
        outv[j] = f2b(cr.fl + ge);
    }
    *(uint4*)(ref_attn + base) = *(uint4*)outv;
}

// ---------------------------------------------------------------------------
// qnew_pre: per row (b,n): softmax(32)@ref_v + q_sc, LN(256) -> ln_t (bf16).
// One WAVE per row, no LDS, no barriers.  grid = 6272 blocks of 256 (4 rows).
// ---------------------------------------------------------------------------
__global__ __launch_bounds__(256) void qnew_pre_kernel(
    const bf16* __restrict__ qkv, const bf16* __restrict__ ref_attn,
    const float* __restrict__ ref_v_t,
    const float* __restrict__ qnw, const float* __restrict__ qnb,
    bf16* __restrict__ ln_t)
{
    int ww = threadIdx.x >> 6, lane = threadIdx.x & 63;
    int row = blockIdx.x * 4 + ww;            // < 25088
    int b = row / 49, n = row % 49;
    int r = b >> 6, w = b & 63;
    int h = lane >> 3, d0 = (lane & 7) * 4;

    const bf16* la = ref_attn + ((size_t)(((r * 8 + h) * 64 + w) * 49 + n)) * 32 + d0;
    ushort4 lu = *(const ushort4*)la;
    float lg[4] = { bu2f(lu.x), bu2f(lu.y), bu2f(lu.z), bu2f(lu.w) };

    float m = fmaxf(fmaxf(lg[0], lg[1]), fmaxf(lg[2], lg[3]));
    m = fmaxf(m, __shfl_xor(m, 1));
    m = fmaxf(m, __shfl_xor(m, 2));
    m = fmaxf(m, __shfl_xor(m, 4));
    float p[4], s = 0.f;
    #pragma unroll
    for (int j = 0; j < 4; ++j) { p[j] = __expf(lg[j] - m); s += p[j]; }
    s += __shfl_xor(s, 1);
    s += __shfl_xor(s, 2);
    s += __shfl_xor(s, 4);
    float inv = 1.f / s;
    #pragma unroll
    for (int j = 0; j < 4; ++j) p[j] *= inv;

    const float* rv = ref_v_t + ((size_t)(r * 8 + h) * 32) * 32 + d0;
    float y[4] = {0.f, 0.f, 0.f, 0.f};
    #pragma unroll
    for (int f = 0; f < 32; ++f) {
        int src = (lane & 56) | (f >> 2);
        float pf = __shfl(p[f & 3], src);
        float4 rvf = *(const float4*)(rv + f * 32);
        y[0] += pf * rvf.x; y[1] += pf * rvf.y;
        y[2] += pf * rvf.z; y[3] += pf * rvf.w;
    }

    ushort4 qu = *(const ushort4*)(qkv + (size_t)row * 768 + lane * 4);
    float z[4] = { y[0] + bu2f(qu.x), y[1] + bu2f(qu.y),
                   y[2] + bu2f(qu.z), y[3] + bu2f(qu.w) };

    float s1 = z[0] + z[1] + z[2] + z[3];
    #pragma unroll
    for (int off = 1; off < 64; off <<= 1) s1 += __shfl_xor(s1, off);
    float mean = s1 * (1.f / 256.f);
    float zc[4] = { z[0] - mean, z[1] - mean, z[2] - mean, z[3] - mean };
    float s2 = zc[0]*zc[0] + zc[1]*zc[1] + zc[2]*zc[2] + zc[3]*zc[3];
    #pragma unroll
    for (int off = 1; off < 64; off <<= 1) s2 += __shfl_xor(s2, off);
    float rstd = rsqrtf(s2 * (1.f / 256.f) + 1e-5f);

    float4 wv = *(const float4*)(qnw + lane * 4);
    float4 bv = *(const float4*)(qnb + lane * 4);
    bf16 outv[4];
    outv[0] = f2b(zc[0] * rstd * wv.x + bv.x);
    outv[1] = f2b(zc[1] * rstd * wv.y + bv.y);
    outv[2] = f2b(zc[2] * rstd * wv.z + bv.z);
    outv[3] = f2b(zc[3] * rstd * wv.w + bv.w);
    *(ushort4*)(ln_t + (size_t)row * 256 + lane * 4) = *(ushort4*)outv;
}

// ---------------------------------------------------------------------------
// MFMA window attention: ONE WAVE per (b,h), no __syncthreads.
// QK: 16 mfma (frags straight from global); softmax in registers
// (16-lane shfl row-reduce); P -> LDS (C->A layout transform);
// V staged transposed (vT[d][m]); PV: 16 mfma.  grid = 1024 blocks of 256.
// ---------------------------------------------------------------------------
__global__ __launch_bounds__(256) void winattn_kernel(
    const bf16* __restrict__ qkv, const bf16* __restrict__ q_new,
    const float* __restrict__ rel_bias, bf16* __restrict__ attn_out)
{
    const int wv = threadIdx.x >> 6, lane = threadIdx.x & 63;
    const int quad = lane >> 4, l15 = lane & 15;
    const int b = blockIdx.x >> 1;
    const int h = (blockIdx.x & 1) * 4 + wv;

    __shared__ bf16 lds[4 * 6912];           // per wave: P[64*72] + vT[32*72]
    bf16* P  = &lds[wv * 6912];
    bf16* vT = P + 4608;

    // ---- stage V transposed: vT[d][m], zero m>=49 ----
    {
        int m = lane;
        if (m < 49) {
            const bf16* vp = qkv + ((size_t)(b * 49 + m)) * 768 + 512 + h * 32;
            V16 v0, v1, v2, v3;
            v0.u4 = *(const uint4*)(vp);
            v1.u4 = *(const uint4*)(vp + 8);
            v2.u4 = *(const uint4*)(vp + 16);
            v3.u4 = *(const uint4*)(vp + 24);
            #pragma unroll
            for (int d = 0; d < 8; ++d) {
                ((unsigned short*)vT)[d * 72 + m]        = v0.s[d];
                ((unsigned short*)vT)[(d + 8) * 72 + m]  = v1.s[d];
                ((unsigned short*)vT)[(d + 16) * 72 + m] = v2.s[d];
                ((unsigned short*)vT)[(d + 24) * 72 + m] = v3.s[d];
            }
        } else {
            #pragma unroll
            for (int d = 0; d < 32; ++d)
                ((unsigned short*)vT)[d * 72 + m] = 0;
        }
    }

    // ---- QK^T: S[tn][tm], frags from global ----
    s16x8 aq[4], bk[4];
    #pragma unroll
    for (int t = 0; t < 4; ++t) {
        int qr = t * 16 + l15; qr = qr > 48 ? 48 : qr;
        aq[t] = ld16g(q_new + ((size_t)(b * 49 + qr)) * 256 + h * 32 + quad * 8);
        bk[t] = ld16g(qkv + ((size_t)(b * 49 + qr)) * 768 + 256 + h * 32 + quad * 8);
    }
    f32x4 S[4][4];
    #pragma unroll
    for (int tn = 0; tn < 4; ++tn)
        #pragma unroll
        for (int tm = 0; tm < 4; ++tm) {
            #pragma unroll
            for (int r = 0; r < 4; ++r) S[tn][tm][r] = 0.f;
            S[tn][tm] = __builtin_amdgcn_mfma_f32_16x16x32_bf16(aq[tn], bk[tm], S[tn][tm], 0, 0, 0);
        }

    // ---- bias + mask + softmax (rows across l15), write P ----
    int mvalid[4], mi[4], mj[4];
    #pragma unroll
    for (int tm = 0; tm < 4; ++tm) {
        int m0 = tm * 16 + l15;
        mvalid[tm] = (m0 < 49);
        int mc = m0 > 48 ? 48 : m0;
        mi[tm] = mc / 7; mj[tm] = mc - mi[tm] * 7;
    }
    #pragma unroll
    for (int tn = 0; tn < 4; ++tn) {
        #pragma unroll
        for (int r = 0; r < 4; ++r) {
            int n0 = tn * 16 + quad * 4 + r;
            int nc = n0 > 48 ? 48 : n0;
            int ni = nc / 7, nj = nc - (nc / 7) * 7;
            float vals[4];
            float mx = -1e30f;
            #pragma unroll
            for (int tm = 0; tm < 4; ++tm) {
                float v = S[tn][tm][r]
                        + rel_bias[((ni - mi[tm] + 6) * 13 + (nj - mj[tm] + 6)) * 8 + h];
                if (!mvalid[tm]) v = -1e30f;
                vals[tm] = v;
                mx = fmaxf(mx, v);
            }
            mx = fmaxf(mx, __shfl_xor(mx, 1));
            mx = fmaxf(mx, __shfl_xor(mx, 2));
            mx = fmaxf(mx, __shfl_xor(mx, 4));
            mx = fmaxf(mx, __shfl_xor(mx, 8));
            float s = 0.f;
            #pragma unroll
            for (int tm = 0; tm < 4; ++tm) { vals[tm] = __expf(vals[tm] - mx); s += vals[tm]; }
            s += __shfl_xor(s, 1);
            s += __shfl_xor(s, 2);
            s += __shfl_xor(s, 4);
            s += __shfl_xor(s, 8);
            float inv = 1.f / s;
            #pragma unroll
            for (int tm = 0; tm < 4; ++tm)
                ((unsigned short*)P)[n0 * 72 + tm * 16 + l15] = f2bs(vals[tm] * inv);
        }
    }

    // ---- PV: O[tn][td] ----
    f32x4 O[4][2];
    #pragma unroll
    for (int tn = 0; tn < 4; ++tn)
        #pragma unroll
        for (int td = 0; td < 2; ++td)
            #pragma unroll
            for (int r = 0; r < 4; ++r) O[tn][td][r] = 0.f;

    #pragma unroll
    for (int ks = 0; ks < 2; ++ks) {
        s16x8 bv0 = *(const s16x8*)&vT[(0 * 16 + l15) * 72 + ks * 32 + quad * 8];
        s16x8 bv1 = *(const s16x8*)&vT[(1 * 16 + l15) * 72 + ks * 32 + quad * 8];
        #pragma unroll
        for (int tn = 0; tn < 4; ++tn) {
            s16x8 ap = *(const s16x8*)&P[(tn * 16 + l15) * 72 + ks * 32 + quad * 8];
            O[tn][0] = __builtin_amdgcn_mfma_f32_16x16x32_bf16(ap, bv0, O[tn][0], 0, 0, 0);
            O[tn][1] = __builtin_amdgcn_mfma_f32_16x16x32_bf16(ap, bv1, O[tn][1], 0, 0, 0);
        }
    }

    // ---- store (C layout: col=l15, row=quad*4+r) ----
    #pragma unroll
    for (int tn = 0; tn < 4; ++tn)
        #pragma unroll
        for (int r = 0; r < 4; ++r) {
            int n0 = tn * 16 + quad * 4 + r;
            if (n0 < 49) {
                size_t base = ((size_t)(b * 49 + n0)) * 256 + h * 32;
                attn_out[base + l15]      = f2b(O[tn][0][r]);
                attn_out[base + 16 + l15] = f2b(O[tn][1][r]);
            }
        }
}

// ---------------------------------------------------------------------------
// Class-token attention per (b,h): both depth & seg.  4096 blocks.
// ---------------------------------------------------------------------------
__global__ __launch_bounds__(256) void clsattn_kernel(
    const bf16* __restrict__ t_k, const bf16* __restrict__ t_v,
    const bf16* __restrict__ depth_q, const bf16* __restrict__ seg_q,
    bf16* __restrict__ d_pre, bf16* __restrict__ s_pre)
{
    int bh = blockIdx.x;
    int b = bh >> 3, h = bh & 7;
    int tid = threadIdx.x;
    __shared__ float tk[2352], tv[2352], dq[392], sq[392], pl[2][384];
    for (int l = tid; l < 2352; l += 256) {
        int n = l / 48, t = l % 48;
        size_t row = (size_t)(b * 49 + n);
        tk[l] = b2f(t_k[row * 384 + h * 48 + t]);
        tv[l] = b2f(t_v[row * 384 + h * 48 + t]);
    }
    for (int l = tid; l < 392; l += 256) {
        int n = l / 8, c = l % 8;
        size_t row = (size_t)(b * 49 + n);
        dq[l] = b2f(depth_q[row * 64 + h * 8 + c]);
        sq[l] = b2f(seg_q[row * 64 + h * 8 + c]);
    }
    __syncthreads();
    for (int l = tid; l < 768; l += 256) {
        int which = l / 384, cc = (l % 384) / 48, t = l % 48;
        const float* q = which ? sq : dq;
        float acc = 0.f;
        for (int n = 0; n < 49; ++n) acc += q[n * 8 + cc] * tk[n * 48 + t];
        pl[which][cc * 48 + t] = acc;
    }
    __syncthreads();
    if (tid < 16) {
        int which = tid >> 3, cc = tid & 7;
        float* p = &pl[which][cc * 48];
        float mx = -1e30f;
        for (int t = 0; t < 48; ++t) mx = fmaxf(mx, p[t]);
        float s = 0.f;
        for (int t = 0; t < 48; ++t) { float e = __expf(p[t] - mx); p[t] = e; s += e; }
        float inv = 1.f / s;
        for (int t = 0; t < 48; ++t) p[t] *= inv;
    }
    __syncthreads();
    for (int l = tid; l < 784; l += 256) {
        int which = l / 392, cc = (l % 392) / 49, n = l % 49;
        const float* p = &pl[which][cc * 48];
        float acc = 0.f;
        for (int t = 0; t < 48; ++t) acc += p[t] * tv[n * 48 + t];
        bf16* outp = which ? s_pre : d_pre;
        outp[(size_t)(b * 49 + n) * 64 + h * 8 + cc] = f2b(acc);
    }
}

// ---------------------------------------------------------------------------
extern "C" void kernel_launch(void* const* d_in, const int* in_sizes, int n_in,
                              void* d_out, int out_size, void* d_ws, size_t ws_size,
                              hipStream_t stream)
{
    const float* x          = (const float*)d_in[0];
    const float* x_ref      = (const float*)d_in[1];
    const float* dth_tok    = (const float*)d_in[2];
    const float* seg_tok    = (const float*)d_in[3];
    const float* qkv_w      = (const float*)d_in[4];
    const float* qkv_b      = (const float*)d_in[5];
    const float* proj_w     = (const float*)d_in[6];
    const float* proj_b     = (const float*)d_in[7];
    const float* rel_bias   = (const float*)d_in[8];
    const float* diff_mu    = (const float*)d_in[9];
    const float* diff_ls    = (const float*)d_in[10];
    const float* ref_qk_w   = (const float*)d_in[11];
    const float* ref_qk_b   = (const float*)d_in[12];
    const float* conv_w     = (const float*)d_in[13];
    const float* conv_b     = (const float*)d_in[14];
    const float* q_norm_w   = (const float*)d_in[15];
    const float* q_norm_b   = (const float*)d_in[16];
    const float* q_proj_w   = (const float*)d_in[17];
    const float* q_proj_b   = (const float*)d_in[18];
    const float* cls_dth_w  = (const float*)d_in[19];
    const float* cls_dth_b  = (const float*)d_in[20];
    const float* cls_seg_w  = (const float*)d_in[21];
    const float* cls_seg_b  = (const float*)d_in[22];
    const float* glob_k_w   = (const float*)d_in[23];
    const float* glob_k_b   = (const float*)d_in[24];
    const float* glob_v_w   = (const float*)d_in[25];
    const float* glob_v_b   = (const float*)d_in[26];
    const float* proj_dth_w = (const float*)d_in[27];
    const float* proj_dth_b = (const float*)d_in[28];

    // ---- workspace layout: total 62.25 MiB ----
    bf16* wsb = (bf16*)d_ws;
    bf16* qkv      = wsb;
    bf16* t_k      = wsb;
    bf16* t_v      = wsb + 9633792;
    bf16* ref_attn = wsb + 19267584;
    bf16* q_new    = ref_attn;
    bf16* depth_q  = ref_attn;
    bf16* seg_q    = ref_attn + 1605632;
    bf16* d_pre    = ref_attn + 3211264;
    bf16* s_pre    = ref_attn + 4816896;
    bf16* u_buf    = wsb + 25690112;
    bf16* ln_t     = u_buf;
    bf16* attn_out = u_buf;
    float* ref_qk  = (float*)((char*)d_ws + 64225280);
    float* ref_q_t = ref_qk + 131072;
    float* ref_v_t = ref_q_t + 65536;
    float* stats   = ref_v_t + 65536;

    float* out0  = (float*)d_out;
    float* out_d = out0 + 6422528;
    float* out_s = out0 + 8028160;

    // 1. qkv = x @ qkv_w + b
    mfma_gemm<<<dim3(12, 392), 256, 0, stream>>>(x, 0, nullptr, nullptr, qkv_w, qkv_b,
                                                 nullptr, 0, nullptr, qkv, 25088, 256, 768, 1.f);
    // 2. ref_qk = x_ref @ ref_qk_w + b
    mfma_gemm<<<dim3(8, 4), 256, 0, stream>>>(x_ref, 0, nullptr, nullptr, ref_qk_w, ref_qk_b,
                                              nullptr, 0, ref_qk, nullptr, 256, 256, 512, 1.f);
    // 3. ref_q_t / ref_v_t
    refprep_kernel<<<256, 256, 0, stream>>>(ref_qk, diff_mu, diff_ls, ref_q_t, ref_v_t);
    // 4. ref_attn scores
    refattn_kernel<<<4096, 256, 0, stream>>>(qkv, ref_q_t, ref_attn);
    // 5. 3x diffusion
    for (int it = 0; it < 3; ++it) {
        conv_kernel<<<392, 256, 0, stream>>>(ref_attn, conv_w, conv_b, u_buf);
        lnstats_kernel<<<64, 256, 0, stream>>>(u_buf, stats);
        lngelu_kernel<<<3136, 256, 0, stream>>>(u_buf, stats, ref_attn);
    }
    // 6. softmax @ ref_v + shortcut + LN -> ln_t
    qnew_pre_kernel<<<6272, 256, 0, stream>>>(qkv, ref_attn, ref_v_t,
                                              q_norm_w, q_norm_b, ln_t);
    // 7. q_new = (ln_t @ q_proj_w + b + qsc) * SCALE
    mfma_gemm<<<dim3(4, 392), 256, 0, stream>>>(ln_t, 1, nullptr, nullptr, q_proj_w, q_proj_b,
                                                qkv, 768, nullptr, q_new, 25088, 256, 256, SCALE_T);
    // 8. window attention (MFMA, 1 wave per (b,h))
    winattn_kernel<<<1024, 256, 0, stream>>>(qkv, q_new, rel_bias, attn_out);
    // 9. out0 = attn_out @ proj_w + b
    mfma_gemm<<<dim3(4, 392), 256, 0, stream>>>(attn_out, 1, nullptr, nullptr, proj_w, proj_b,
                                                nullptr, 0, out0, nullptr, 25088, 256, 256, 1.f);
    // 10/11. t_k, t_v
    mfma_gemm<<<dim3(6, 392), 256, 0, stream>>>(out0, 2, dth_tok, seg_tok, glob_k_w, glob_k_b,
                                                nullptr, 0, nullptr, t_k, 25088, 384, 384, 1.f);
    mfma_gemm<<<dim3(6, 392), 256, 0, stream>>>(out0, 2, dth_tok, seg_tok, glob_v_w, glob_v_b,
                                                nullptr, 0, nullptr, t_v, 25088, 384, 384, 1.f);
    // 12/13. depth_q, seg_q
    mfma_gemm<<<dim3(1, 392), 256, 0, stream>>>(dth_tok, 0, nullptr, nullptr, cls_dth_w, cls_dth_b,
                                                nullptr, 0, nullptr, depth_q, 25088, 64, 64, SCALE_T);
    mfma_gemm<<<dim3(1, 392), 256, 0, stream>>>(seg_tok, 0, nullptr, nullptr, cls_seg_w, cls_seg_b,
                                                nullptr, 0, nullptr, seg_q, 25088, 64, 64, SCALE_T);
    // 14. class-token attention
    clsattn_kernel<<<4096, 256, 0, stream>>>(t_k, t_v, depth_q, seg_q, d_pre, s_pre);
    // 15/16. final proj_dth
    mfma_gemm<<<dim3(1, 392), 256, 0, stream>>>(d_pre, 1, nullptr, nullptr, proj_dth_w, proj_dth_b,
                                                nullptr, 0, out_d, nullptr, 25088, 64, 64, 1.f);
    mfma_gemm<<<dim3(1, 392), 256, 0, stream>>>(s_pre, 1, nullptr, nullptr, proj_dth_w, proj_dth_b,
                                                nullptr, 0, out_s, nullptr, 25088, 64, 64, 1.f);
}

// Round 9
// 583.581 us; speedup vs baseline: 3.6492x; 1.0850x over previous
//
#include <hip/hip_runtime.h>
#include <hip/hip_bf16.h>

typedef __hip_bfloat16 bf16;
typedef short s16x8 __attribute__((ext_vector_type(8)));
typedef float f32x4 __attribute__((ext_vector_type(4)));
union V16 { uint4 u4; s16x8 s8; unsigned u[4]; unsigned short s[8]; };

static __device__ __forceinline__ float b2f(bf16 v){ return __bfloat162float(v); }
static __device__ __forceinline__ bf16  f2b(float v){ return __float2bfloat16(v); }
static __device__ __forceinline__ unsigned short f2bs(float x){
    union { float f; unsigned u; } c; c.f = x;
    unsigned r = c.u + 0x7fff + ((c.u >> 16) & 1);
    return (unsigned short)(r >> 16);
}
static __device__ __forceinline__ float bu2f(unsigned short b){
    union { unsigned u; float f; } c; c.u = ((unsigned)b) << 16; return c.f;
}
static __device__ __forceinline__ s16x8 ld16g(const bf16* p){
    V16 u; u.u4 = *(const uint4*)p; return u.s8;
}

#define SCALE_T 0.17677669529663687f   // 32^-0.5

// ---------------------------------------------------------------------------
// MFMA bf16 GEMM: out = (A[M,K] @ W[K,N] + bias [+ add]) * scale
// 64x64 tile, BK=32, 256 threads (4 waves), v_mfma_f32_16x16x32_bf16.
// a_mode: 0 = A f32 [M,K]; 1 = A bf16 [M,K] (ws intermediate);
//         2 = A = concat(A f32[M,256], Xd f32[M,64], Xs f32[M,64]) (K=384)
// ---------------------------------------------------------------------------
__global__ __launch_bounds__(256) void mfma_gemm(
    const void* __restrict__ A, int a_mode,
    const float* __restrict__ Xd, const float* __restrict__ Xs,
    const float* __restrict__ W, const float* __restrict__ bias,
    const bf16* __restrict__ addp, int addStride,
    float* __restrict__ outF, bf16* __restrict__ outB,
    int M, int K, int N, float scale)
{
    __shared__ __hip_bfloat16 Al[64][48];
    __shared__ __hip_bfloat16 Bl[64][48];

    const int tid  = threadIdx.x;
    const int wv   = tid >> 6, lane = tid & 63;
    const int quad = lane >> 4, l15 = lane & 15;
    const int rowBase = blockIdx.y * 64, colBase = blockIdx.x * 64;

    const int am = tid >> 2, ak = (tid & 3) * 8;
    const int bn = tid & 63, bk = (tid >> 6) * 8;

    f32x4 acc[4];
    #pragma unroll
    for (int t = 0; t < 4; ++t)
        #pragma unroll
        for (int r = 0; r < 4; ++r) acc[t][r] = 0.f;

    for (int kt = 0; kt < K; kt += 32) {
        s16x8 sa;
        if (a_mode == 1) {
            const bf16* Ab = (const bf16*)A;
            V16 u; u.u4 = *(const uint4*)(Ab + (size_t)(rowBase + am) * K + kt + ak);
            sa = u.s8;
        } else {
            const float* src; size_t base;
            if (a_mode == 0) {
                src = (const float*)A; base = (size_t)(rowBase + am) * K + kt + ak;
            } else {
                int kcol = kt + ak;
                if (kcol < 256)      { src = (const float*)A; base = (size_t)(rowBase + am) * 256 + kcol; }
                else if (kcol < 320) { src = Xd; base = (size_t)(rowBase + am) * 64 + (kcol - 256); }
                else                 { src = Xs; base = (size_t)(rowBase + am) * 64 + (kcol - 320); }
            }
            const float4* p = (const float4*)(src + base);
            float4 u0 = p[0], u1 = p[1];
            sa[0] = (short)f2bs(u0.x); sa[1] = (short)f2bs(u0.y);
            sa[2] = (short)f2bs(u0.z); sa[3] = (short)f2bs(u0.w);
            sa[4] = (short)f2bs(u1.x); sa[5] = (short)f2bs(u1.y);
            sa[6] = (short)f2bs(u1.z); sa[7] = (short)f2bs(u1.w);
        }
        *(s16x8*)&Al[am][ak] = sa;

        s16x8 sb;
        #pragma unroll
        for (int j = 0; j < 8; ++j)
            sb[j] = (short)f2bs(W[(size_t)(kt + bk + j) * N + colBase + bn]);
        *(s16x8*)&Bl[bn][bk] = sb;

        __syncthreads();

        s16x8 a = *(const s16x8*)&Al[wv * 16 + l15][quad * 8];
        #pragma unroll
        for (int t = 0; t < 4; ++t) {
            s16x8 b = *(const s16x8*)&Bl[t * 16 + l15][quad * 8];
            acc[t] = __builtin_amdgcn_mfma_f32_16x16x32_bf16(a, b, acc[t], 0, 0, 0);
        }
        __syncthreads();
    }

    #pragma unroll
    for (int t = 0; t < 4; ++t) {
        int col = colBase + t * 16 + l15;
        float bb = bias[col];
        #pragma unroll
        for (int r = 0; r < 4; ++r) {
            int row = rowBase + wv * 16 + quad * 4 + r;
            float v = acc[t][r] + bb;
            if (addp) v += b2f(addp[(size_t)row * addStride + col]);
            v *= scale;
            if (outF) outF[(size_t)row * N + col] = v;
            if (outB) outB[(size_t)row * N + col] = f2b(v);
        }
    }
}

// ---------------------------------------------------------------------------
// ref_q_t[r,h,f,d] = mu[c] + exp(ls[c]) * ref_qk[r*32+f, c];  ref_v_t from +256
// ---------------------------------------------------------------------------
__global__ __launch_bounds__(256) void refprep_kernel(
    const float* __restrict__ ref_qk, const float* __restrict__ mu,
    const float* __restrict__ ls, float* __restrict__ ref_q_t,
    float* __restrict__ ref_v_t)
{
    int idx = blockIdx.x * 256 + threadIdx.x;          // [r,h,f,d]
    int d = idx & 31, f = (idx >> 5) & 31, h = (idx >> 10) & 7, r = idx >> 13;
    int c = h * 32 + d;
    size_t src = (size_t)(r * 32 + f) * 512 + c;
    ref_q_t[idx] = mu[c] + __expf(ls[c]) * ref_qk[src];
    ref_v_t[idx] = ref_qk[src + 256];
}

// ---------------------------------------------------------------------------
// ref_attn[r,h,w,n,f] = sum_d (q[b,h,n,d]*SCALE) * ref_q_t[r,h,f,d]
// ---------------------------------------------------------------------------
__global__ __launch_bounds__(256) void refattn_kernel(
    const bf16* __restrict__ qkv, const float* __restrict__ ref_q_t,
    bf16* __restrict__ ref_attn)
{
    int blk = blockIdx.x;
    int w = blk & 63, h = (blk >> 6) & 7, r = blk >> 9;
    int b = r * 64 + w;
    __shared__ float qt[49 * 32];
    __shared__ float rq[32 * 33];
    int tid = threadIdx.x;
    for (int l = tid; l < 1568; l += 256) {
        int n = l >> 5, d = l & 31;
        qt[l] = b2f(qkv[(size_t)(b * 49 + n) * 768 + h * 32 + d]) * SCALE_T;
    }
    for (int l = tid; l < 1024; l += 256) {
        int f = l >> 5, d = l & 31;
        rq[f * 33 + d] = ref_q_t[(size_t)((r * 8 + h) * 32 + f) * 32 + d];
    }
    __syncthreads();
    for (int l = tid; l < 1568; l += 256) {
        int n = l >> 5, f = l & 31;
        float acc = 0.f;
        #pragma unroll
        for (int d2 = 0; d2 < 32; ++d2) acc += qt[n * 32 + d2] * rq[f * 33 + d2];
        ref_attn[(size_t)(((r * 8 + h) * 64 + w) * 49 + n) * 32 + f] = f2b(acc);
    }
}

// ---------------------------------------------------------------------------
// 3x3 SAME conv over [RB=8, 8ch, 3136, 32].
// ---------------------------------------------------------------------------
__global__ __launch_bounds__(256) void conv_kernel(
    const bf16* __restrict__ in, const float* __restrict__ conv_w,
    const float* __restrict__ conv_b, bf16* __restrict__ u)
{
    __shared__ float w_s[576];
    __shared__ float b_s[8];
    int tid = threadIdx.x;
    for (int l = tid; l < 576; l += 256) w_s[l] = conv_w[l];
    if (tid < 8) b_s[tid] = conv_b[tid];
    __syncthreads();

    int idx = blockIdx.x * 256 + tid;          // < 100352
    int fb = idx & 3;
    int p  = (idx >> 2) % 3136;
    int r  = idx / 12544;
    int f0 = fb * 8;

    float acc[8][8];
    #pragma unroll
    for (int o = 0; o < 8; ++o) {
        float bo = b_s[o];
        #pragma unroll
        for (int f = 0; f < 8; ++f) acc[o][f] = bo;
    }

    for (int i = 0; i < 8; ++i) {
        float ext[3][10];
        #pragma unroll
        for (int dy = 0; dy < 3; ++dy) {
            int pp = p + dy - 1;
            bool pv = (unsigned)pp < 3136u;
            size_t base = ((size_t)((r * 8 + i) * 3136 + (pv ? pp : 0))) * 32 + f0;
            V16 uv;
            uv.u4 = pv ? *(const uint4*)(in + base) : make_uint4(0, 0, 0, 0);
            #pragma unroll
            for (int j = 0; j < 8; ++j) {
                unsigned sh = uv.u[j >> 1];
                unsigned bits = (j & 1) ? (sh & 0xffff0000u) : (sh << 16);
                union { unsigned uu; float fl; } cv; cv.uu = bits;
                ext[dy][j + 1] = cv.fl;
            }
            ext[dy][0] = (pv && f0 > 0)      ? b2f(in[base - 1]) : 0.f;
            ext[dy][9] = (pv && f0 + 8 < 32) ? b2f(in[base + 8]) : 0.f;
        }
        #pragma unroll
        for (int o = 0; o < 8; ++o) {
            #pragma unroll
            for (int ky = 0; ky < 3; ++ky) {
                const float* wp = &w_s[((o * 8 + i) * 3 + ky) * 3];
                float w0 = wp[0], w1 = wp[1], w2 = wp[2];
                #pragma unroll
                for (int f = 0; f < 8; ++f)
                    acc[o][f] += ext[ky][f] * w0 + ext[ky][f + 1] * w1 + ext[ky][f + 2] * w2;
            }
        }
    }

    #pragma unroll
    for (int o = 0; o < 8; ++o) {
        bf16 ov[8];
        #pragma unroll
        for (int f = 0; f < 8; ++f) ov[f] = f2b(acc[o][f]);
        *(uint4*)(u + ((size_t)((r * 8 + o) * 3136 + p)) * 32 + f0) = *(uint4*)ov;
    }
}

// ---------------------------------------------------------------------------
// Per-(r,ch) mean/rstd over contiguous 100352-elem map.  64 blocks, bf16x8.
// ---------------------------------------------------------------------------
__global__ __launch_bounds__(256) void lnstats_kernel(
    const bf16* __restrict__ u, float* __restrict__ stats)
{
    int g = blockIdx.x;
    const bf16* p = u + (size_t)g * 100352;
    int tid = threadIdx.x;
    float s = 0.f, s2 = 0.f;
    for (int it = tid; it < 12544; it += 256) {
        V16 uv; uv.u4 = *(const uint4*)(p + it * 8);
        #pragma unroll
        for (int j = 0; j < 8; ++j) {
            unsigned sh = uv.u[j >> 1];
            unsigned bits = (j & 1) ? (sh & 0xffff0000u) : (sh << 16);
            union { unsigned uu; float fl; } cv; cv.uu = bits;
            s += cv.fl; s2 += cv.fl * cv.fl;
        }
    }
    __shared__ float r1[256], r2[256];
    r1[tid] = s; r2[tid] = s2; __syncthreads();
    for (int st = 128; st > 0; st >>= 1) {
        if (tid < st) { r1[tid] += r1[tid + st]; r2[tid] += r2[tid + st]; }
        __syncthreads();
    }
    if (tid == 0) {
        float mean = r1[0] * (1.f / 100352.f);
        float var  = r2[0] * (1.f / 100352.f) - mean * mean;
        var = fmaxf(var, 0.f);
        stats[g * 2] = mean;
        stats[g * 2 + 1] = rsqrtf(var + 1e-5f);
    }
}

// ref_attn += gelu_exact( (u - mean) * rstd );  bf16x8, grid = 3136 blocks.
__global__ __launch_bounds__(256) void lngelu_kernel(
    const bf16* __restrict__ u, const float* __restrict__ stats,
    bf16* __restrict__ ref_attn)
{
    int idx8 = blockIdx.x * 256 + threadIdx.x;    // < 802816
    int g = idx8 / 12544;
    size_t base = (size_t)idx8 * 8;
    float mean = stats[g * 2], rstd = stats[g * 2 + 1];
    V16 uv; uv.u4 = *(const uint4*)(u + base);
    V16 rv; rv.u4 = *(const uint4*)(ref_attn + base);
    bf16 outv[8];
    #pragma unroll
    for (int j = 0; j < 8; ++j) {
        unsigned shu = uv.u[j >> 1];
        unsigned shr = rv.u[j >> 1];
        unsigned bu = (j & 1) ? (shu & 0xffff0000u) : (shu << 16);
        unsigned br = (j & 1) ? (shr & 0xffff0000u) : (shr << 16);
        union { unsigned uu; float fl; } cu, cr; cu.uu = bu; cr.uu = br;
        float v = (cu.fl - mean) * rstd;
        float ge = 0.5f * v * (1.f + erff(v * 0.7071067811865476f));
        outv[j] = f2b(cr.fl + ge);
    }
    *(uint4*)(ref_attn + base) = *(uint4*)outv;
}

// ---------------------------------------------------------------------------
// qnew_pre: per row (b,n): softmax(32)@ref_v + q_sc, LN(256) -> ln_t (bf16).
// One WAVE per row, no LDS, no barriers.  grid = 6272 blocks of 256 (4 rows).
// ---------------------------------------------------------------------------
__global__ __launch_bounds__(256) void qnew_pre_kernel(
    const bf16* __restrict__ qkv, const bf16* __restrict__ ref_attn,
    const float* __restrict__ ref_v_t,
    const float* __restrict__ qnw, const float* __restrict__ qnb,
    bf16* __restrict__ ln_t)
{
    int ww = threadIdx.x >> 6, lane = threadIdx.x & 63;
    int row = blockIdx.x * 4 + ww;            // < 25088
    int b = row / 49, n = row % 49;
    int r = b >> 6, w = b & 63;
    int h = lane >> 3, d0 = (lane & 7) * 4;

    const bf16* la = ref_attn + ((size_t)(((r * 8 + h) * 64 + w) * 49 + n)) * 32 + d0;
    ushort4 lu = *(const ushort4*)la;
    float lg[4] = { bu2f(lu.x), bu2f(lu.y), bu2f(lu.z), bu2f(lu.w) };

    float m = fmaxf(fmaxf(lg[0], lg[1]), fmaxf(lg[2], lg[3]));
    m = fmaxf(m, __shfl_xor(m, 1));
    m = fmaxf(m, __shfl_xor(m, 2));
    m = fmaxf(m, __shfl_xor(m, 4));
    float p[4], s = 0.f;
    #pragma unroll
    for (int j = 0; j < 4; ++j) { p[j] = __expf(lg[j] - m); s += p[j]; }
    s += __shfl_xor(s, 1);
    s += __shfl_xor(s, 2);
    s += __shfl_xor(s, 4);
    float inv = 1.f / s;
    #pragma unroll
    for (int j = 0; j < 4; ++j) p[j] *= inv;

    const float* rv = ref_v_t + ((size_t)(r * 8 + h) * 32) * 32 + d0;
    float y[4] = {0.f, 0.f, 0.f, 0.f};
    #pragma unroll
    for (int f = 0; f < 32; ++f) {
        int src = (lane & 56) | (f >> 2);
        float pf = __shfl(p[f & 3], src);
        float4 rvf = *(const float4*)(rv + f * 32);
        y[0] += pf * rvf.x; y[1] += pf * rvf.y;
        y[2] += pf * rvf.z; y[3] += pf * rvf.w;
    }

    ushort4 qu = *(const ushort4*)(qkv + (size_t)row * 768 + lane * 4);
    float z[4] = { y[0] + bu2f(qu.x), y[1] + bu2f(qu.y),
                   y[2] + bu2f(qu.z), y[3] + bu2f(qu.w) };

    float s1 = z[0] + z[1] + z[2] + z[3];
    #pragma unroll
    for (int off = 1; off < 64; off <<= 1) s1 += __shfl_xor(s1, off);
    float mean = s1 * (1.f / 256.f);
    float zc[4] = { z[0] - mean, z[1] - mean, z[2] - mean, z[3] - mean };
    float s2 = zc[0]*zc[0] + zc[1]*zc[1] + zc[2]*zc[2] + zc[3]*zc[3];
    #pragma unroll
    for (int off = 1; off < 64; off <<= 1) s2 += __shfl_xor(s2, off);
    float rstd = rsqrtf(s2 * (1.f / 256.f) + 1e-5f);

    float4 wv = *(const float4*)(qnw + lane * 4);
    float4 bv = *(const float4*)(qnb + lane * 4);
    bf16 outv[4];
    outv[0] = f2b(zc[0] * rstd * wv.x + bv.x);
    outv[1] = f2b(zc[1] * rstd * wv.y + bv.y);
    outv[2] = f2b(zc[2] * rstd * wv.z + bv.z);
    outv[3] = f2b(zc[3] * rstd * wv.w + bv.w);
    *(ushort4*)(ln_t + (size_t)row * 256 + lane * 4) = *(ushort4*)outv;
}

// ---------------------------------------------------------------------------
// MFMA window attention: ONE WAVE per (b,h), no __syncthreads.
// ---------------------------------------------------------------------------
__global__ __launch_bounds__(256) void winattn_kernel(
    const bf16* __restrict__ qkv, const bf16* __restrict__ q_new,
    const float* __restrict__ rel_bias, bf16* __restrict__ attn_out)
{
    const int wv = threadIdx.x >> 6, lane = threadIdx.x & 63;
    const int quad = lane >> 4, l15 = lane & 15;
    const int b = blockIdx.x >> 1;
    const int h = (blockIdx.x & 1) * 4 + wv;

    __shared__ bf16 lds[4 * 6912];           // per wave: P[64*72] + vT[32*72]
    bf16* P  = &lds[wv * 6912];
    bf16* vT = P + 4608;

    {
        int m = lane;
        if (m < 49) {
            const bf16* vp = qkv + ((size_t)(b * 49 + m)) * 768 + 512 + h * 32;
            V16 v0, v1, v2, v3;
            v0.u4 = *(const uint4*)(vp);
            v1.u4 = *(const uint4*)(vp + 8);
            v2.u4 = *(const uint4*)(vp + 16);
            v3.u4 = *(const uint4*)(vp + 24);
            #pragma unroll
            for (int d = 0; d < 8; ++d) {
                ((unsigned short*)vT)[d * 72 + m]        = v0.s[d];
                ((unsigned short*)vT)[(d + 8) * 72 + m]  = v1.s[d];
                ((unsigned short*)vT)[(d + 16) * 72 + m] = v2.s[d];
                ((unsigned short*)vT)[(d + 24) * 72 + m] = v3.s[d];
            }
        } else {
            #pragma unroll
            for (int d = 0; d < 32; ++d)
                ((unsigned short*)vT)[d * 72 + m] = 0;
        }
    }

    s16x8 aq[4], bk[4];
    #pragma unroll
    for (int t = 0; t < 4; ++t) {
        int qr = t * 16 + l15; qr = qr > 48 ? 48 : qr;
        aq[t] = ld16g(q_new + ((size_t)(b * 49 + qr)) * 256 + h * 32 + quad * 8);
        bk[t] = ld16g(qkv + ((size_t)(b * 49 + qr)) * 768 + 256 + h * 32 + quad * 8);
    }
    f32x4 S[4][4];
    #pragma unroll
    for (int tn = 0; tn < 4; ++tn)
        #pragma unroll
        for (int tm = 0; tm < 4; ++tm) {
            #pragma unroll
            for (int r = 0; r < 4; ++r) S[tn][tm][r] = 0.f;
            S[tn][tm] = __builtin_amdgcn_mfma_f32_16x16x32_bf16(aq[tn], bk[tm], S[tn][tm], 0, 0, 0);
        }

    int mvalid[4], mi[4], mj[4];
    #pragma unroll
    for (int tm = 0; tm < 4; ++tm) {
        int m0 = tm * 16 + l15;
        mvalid[tm] = (m0 < 49);
        int mc = m0 > 48 ? 48 : m0;
        mi[tm] = mc / 7; mj[tm] = mc - mi[tm] * 7;
    }
    #pragma unroll
    for (int tn = 0; tn < 4; ++tn) {
        #pragma unroll
        for (int r = 0; r < 4; ++r) {
            int n0 = tn * 16 + quad * 4 + r;
            int nc = n0 > 48 ? 48 : n0;
            int ni = nc / 7, nj = nc - (nc / 7) * 7;
            float vals[4];
            float mx = -1e30f;
            #pragma unroll
            for (int tm = 0; tm < 4; ++tm) {
                float v = S[tn][tm][r]
                        + rel_bias[((ni - mi[tm] + 6) * 13 + (nj - mj[tm] + 6)) * 8 + h];
                if (!mvalid[tm]) v = -1e30f;
                vals[tm] = v;
                mx = fmaxf(mx, v);
            }
            mx = fmaxf(mx, __shfl_xor(mx, 1));
            mx = fmaxf(mx, __shfl_xor(mx, 2));
            mx = fmaxf(mx, __shfl_xor(mx, 4));
            mx = fmaxf(mx, __shfl_xor(mx, 8));
            float s = 0.f;
            #pragma unroll
            for (int tm = 0; tm < 4; ++tm) { vals[tm] = __expf(vals[tm] - mx); s += vals[tm]; }
            s += __shfl_xor(s, 1);
            s += __shfl_xor(s, 2);
            s += __shfl_xor(s, 4);
            s += __shfl_xor(s, 8);
            float inv = 1.f / s;
            #pragma unroll
            for (int tm = 0; tm < 4; ++tm)
                ((unsigned short*)P)[n0 * 72 + tm * 16 + l15] = f2bs(vals[tm] * inv);
        }
    }

    f32x4 O[4][2];
    #pragma unroll
    for (int tn = 0; tn < 4; ++tn)
        #pragma unroll
        for (int td = 0; td < 2; ++td)
            #pragma unroll
            for (int r = 0; r < 4; ++r) O[tn][td][r] = 0.f;

    #pragma unroll
    for (int ks = 0; ks < 2; ++ks) {
        s16x8 bv0 = *(const s16x8*)&vT[(0 * 16 + l15) * 72 + ks * 32 + quad * 8];
        s16x8 bv1 = *(const s16x8*)&vT[(1 * 16 + l15) * 72 + ks * 32 + quad * 8];
        #pragma unroll
        for (int tn = 0; tn < 4; ++tn) {
            s16x8 ap = *(const s16x8*)&P[(tn * 16 + l15) * 72 + ks * 32 + quad * 8];
            O[tn][0] = __builtin_amdgcn_mfma_f32_16x16x32_bf16(ap, bv0, O[tn][0], 0, 0, 0);
            O[tn][1] = __builtin_amdgcn_mfma_f32_16x16x32_bf16(ap, bv1, O[tn][1], 0, 0, 0);
        }
    }

    #pragma unroll
    for (int tn = 0; tn < 4; ++tn)
        #pragma unroll
        for (int r = 0; r < 4; ++r) {
            int n0 = tn * 16 + quad * 4 + r;
            if (n0 < 49) {
                size_t base = ((size_t)(b * 49 + n0)) * 256 + h * 32;
                attn_out[base + l15]      = f2b(O[tn][0][r]);
                attn_out[base + 16 + l15] = f2b(O[tn][1][r]);
            }
        }
}

// ---------------------------------------------------------------------------
// MFMA class-token attention: ONE WAVE per (b,h), no __syncthreads.
// M=16 stacks depth(c 0..7) + seg(c 8..15).  QK: S[c,t]=sum_n q[n,c]k[n,t]
// (K=n pad 64, zeros in both operands -> exact).  softmax over t=48.
// PV: O[c,n]=sum_t P[c,t]v[n,t] (K=t pad 64 zeros).  grid = 1024 x 256.
// LDS/wave: QP 16x72 (qT then P), KV 64x72 (tkT[t][n] then tv[n][t]).
// ---------------------------------------------------------------------------
__global__ __launch_bounds__(256) void clsattn_kernel(
    const bf16* __restrict__ t_k, const bf16* __restrict__ t_v,
    const bf16* __restrict__ depth_q, const bf16* __restrict__ seg_q,
    bf16* __restrict__ d_pre, bf16* __restrict__ s_pre)
{
    const int wv = threadIdx.x >> 6, lane = threadIdx.x & 63;
    const int quad = lane >> 4, l15 = lane & 15;
    const int bh = blockIdx.x * 4 + wv;      // < 4096
    const int b = bh >> 3, h = bh & 7;

    __shared__ bf16 lds[4 * 5760];
    unsigned short* QP = (unsigned short*)&lds[wv * 5760];   // 16 x 72
    unsigned short* KV = QP + 1152;                          // 64 x 72 (max use 4608)

    // ---- stage qT[16][n] (depth rows 0-7, seg rows 8-15; zero n>=49) ----
    {
        int n = lane;
        V16 dv, sv;
        if (n < 49) {
            dv.u4 = *(const uint4*)(depth_q + ((size_t)(b * 49 + n)) * 64 + h * 8);
            sv.u4 = *(const uint4*)(seg_q   + ((size_t)(b * 49 + n)) * 64 + h * 8);
        } else {
            dv.u4 = make_uint4(0, 0, 0, 0); sv.u4 = make_uint4(0, 0, 0, 0);
        }
        #pragma unroll
        for (int c = 0; c < 8; ++c) {
            QP[c * 72 + n]       = dv.s[c];
            QP[(8 + c) * 72 + n] = sv.s[c];
        }
    }
    // ---- stage tkT[t][n] (zero n>=49) ----
    {
        int n = lane;
        V16 k[6];
        if (n < 49) {
            const bf16* kp = t_k + ((size_t)(b * 49 + n)) * 384 + h * 48;
            #pragma unroll
            for (int c6 = 0; c6 < 6; ++c6) k[c6].u4 = *(const uint4*)(kp + c6 * 8);
        } else {
            #pragma unroll
            for (int c6 = 0; c6 < 6; ++c6) k[c6].u4 = make_uint4(0, 0, 0, 0);
        }
        #pragma unroll
        for (int c6 = 0; c6 < 6; ++c6)
            #pragma unroll
            for (int j = 0; j < 8; ++j)
                KV[(c6 * 8 + j) * 72 + n] = k[c6].s[j];
    }

    // ---- QK: S[c=16 rows][t=48 cols], 2 K-steps x 3 t-tiles ----
    f32x4 S[3];
    #pragma unroll
    for (int t3 = 0; t3 < 3; ++t3)
        #pragma unroll
        for (int r = 0; r < 4; ++r) S[t3][r] = 0.f;
    #pragma unroll
    for (int ks = 0; ks < 2; ++ks) {
        s16x8 a = *(const s16x8*)&QP[l15 * 72 + ks * 32 + quad * 8];
        #pragma unroll
        for (int t3 = 0; t3 < 3; ++t3) {
            s16x8 bf = *(const s16x8*)&KV[(t3 * 16 + l15) * 72 + ks * 32 + quad * 8];
            S[t3] = __builtin_amdgcn_mfma_f32_16x16x32_bf16(a, bf, S[t3], 0, 0, 0);
        }
    }

    // ---- softmax over t (48) per row c = quad*4+r; write P[c][t] into QP ----
    #pragma unroll
    for (int r = 0; r < 4; ++r) {
        float v0 = S[0][r], v1 = S[1][r], v2 = S[2][r];
        float mx = fmaxf(fmaxf(v0, v1), v2);
        mx = fmaxf(mx, __shfl_xor(mx, 1));
        mx = fmaxf(mx, __shfl_xor(mx, 2));
        mx = fmaxf(mx, __shfl_xor(mx, 4));
        mx = fmaxf(mx, __shfl_xor(mx, 8));
        float e0 = __expf(v0 - mx), e1 = __expf(v1 - mx), e2 = __expf(v2 - mx);
        float s = e0 + e1 + e2;
        s += __shfl_xor(s, 1);
        s += __shfl_xor(s, 2);
        s += __shfl_xor(s, 4);
        s += __shfl_xor(s, 8);
        float inv = 1.f / s;
        int c = quad * 4 + r;
        QP[c * 72 + 0 * 16 + l15] = f2bs(e0 * inv);
        QP[c * 72 + 1 * 16 + l15] = f2bs(e1 * inv);
        QP[c * 72 + 2 * 16 + l15] = f2bs(e2 * inv);
    }
    // zero P cols t=48..63 (K-pad)
    #pragma unroll
    for (int z = 0; z < 4; ++z)
        QP[(lane & 15) * 72 + 48 + (lane >> 4) * 4 + z] = 0;

    // ---- stage tv[n][t] rows (t cols 48..63 zero; rows n>=49 zero) ----
    {
        int n = lane;
        V16 v[6], zv; zv.u4 = make_uint4(0, 0, 0, 0);
        if (n < 49) {
            const bf16* vp = t_v + ((size_t)(b * 49 + n)) * 384 + h * 48;
            #pragma unroll
            for (int c6 = 0; c6 < 6; ++c6) v[c6].u4 = *(const uint4*)(vp + c6 * 8);
        } else {
            #pragma unroll
            for (int c6 = 0; c6 < 6; ++c6) v[c6].u4 = zv.u4;
        }
        #pragma unroll
        for (int c6 = 0; c6 < 6; ++c6)
            *(uint4*)&KV[n * 72 + c6 * 8] = v[c6].u4;
        *(uint4*)&KV[n * 72 + 48] = zv.u4;
        *(uint4*)&KV[n * 72 + 56] = zv.u4;
    }

    // ---- PV: O[c][n], 2 K-steps x 4 n-tiles ----
    f32x4 O[4];
    #pragma unroll
    for (int t4 = 0; t4 < 4; ++t4)
        #pragma unroll
        for (int r = 0; r < 4; ++r) O[t4][r] = 0.f;
    #pragma unroll
    for (int ks = 0; ks < 2; ++ks) {
        s16x8 a = *(const s16x8*)&QP[l15 * 72 + ks * 32 + quad * 8];
        #pragma unroll
        for (int t4 = 0; t4 < 4; ++t4) {
            s16x8 bf = *(const s16x8*)&KV[(t4 * 16 + l15) * 72 + ks * 32 + quad * 8];
            O[t4] = __builtin_amdgcn_mfma_f32_16x16x32_bf16(a, bf, O[t4], 0, 0, 0);
        }
    }

    // ---- store: col=n=l15(tile), row=c=quad*4+r; c<8 -> d_pre, else s_pre ----
    #pragma unroll
    for (int t4 = 0; t4 < 4; ++t4) {
        int n = t4 * 16 + l15;
        if (n < 49) {
            size_t base = ((size_t)(b * 49 + n)) * 64 + h * 8;
            #pragma unroll
            for (int r = 0; r < 4; ++r) {
                int c = quad * 4 + r;
                if (c < 8) d_pre[base + c] = f2b(O[t4][r]);
                else       s_pre[base + c - 8] = f2b(O[t4][r]);
            }
        }
    }
}

// ---------------------------------------------------------------------------
extern "C" void kernel_launch(void* const* d_in, const int* in_sizes, int n_in,
                              void* d_out, int out_size, void* d_ws, size_t ws_size,
                              hipStream_t stream)
{
    const float* x          = (const float*)d_in[0];
    const float* x_ref      = (const float*)d_in[1];
    const float* dth_tok    = (const float*)d_in[2];
    const float* seg_tok    = (const float*)d_in[3];
    const float* qkv_w      = (const float*)d_in[4];
    const float* qkv_b      = (const float*)d_in[5];
    const float* proj_w     = (const float*)d_in[6];
    const float* proj_b     = (const float*)d_in[7];
    const float* rel_bias   = (const float*)d_in[8];
    const float* diff_mu    = (const float*)d_in[9];
    const float* diff_ls    = (const float*)d_in[10];
    const float* ref_qk_w   = (const float*)d_in[11];
    const float* ref_qk_b   = (const float*)d_in[12];
    const float* conv_w     = (const float*)d_in[13];
    const float* conv_b     = (const float*)d_in[14];
    const float* q_norm_w   = (const float*)d_in[15];
    const float* q_norm_b   = (const float*)d_in[16];
    const float* q_proj_w   = (const float*)d_in[17];
    const float* q_proj_b   = (const float*)d_in[18];
    const float* cls_dth_w  = (const float*)d_in[19];
    const float* cls_dth_b  = (const float*)d_in[20];
    const float* cls_seg_w  = (const float*)d_in[21];
    const float* cls_seg_b  = (const float*)d_in[22];
    const float* glob_k_w   = (const float*)d_in[23];
    const float* glob_k_b   = (const float*)d_in[24];
    const float* glob_v_w   = (const float*)d_in[25];
    const float* glob_v_b   = (const float*)d_in[26];
    const float* proj_dth_w = (const float*)d_in[27];
    const float* proj_dth_b = (const float*)d_in[28];

    // ---- workspace layout: total 62.25 MiB ----
    bf16* wsb = (bf16*)d_ws;
    bf16* qkv      = wsb;
    bf16* t_k      = wsb;
    bf16* t_v      = wsb + 9633792;
    bf16* ref_attn = wsb + 19267584;
    bf16* q_new    = ref_attn;
    bf16* depth_q  = ref_attn;
    bf16* seg_q    = ref_attn + 1605632;
    bf16* d_pre    = ref_attn + 3211264;
    bf16* s_pre    = ref_attn + 4816896;
    bf16* u_buf    = wsb + 25690112;
    bf16* ln_t     = u_buf;
    bf16* attn_out = u_buf;
    float* ref_qk  = (float*)((char*)d_ws + 64225280);
    float* ref_q_t = ref_qk + 131072;
    float* ref_v_t = ref_q_t + 65536;
    float* stats   = ref_v_t + 65536;

    float* out0  = (float*)d_out;
    float* out_d = out0 + 6422528;
    float* out_s = out0 + 8028160;

    // 1. qkv = x @ qkv_w + b
    mfma_gemm<<<dim3(12, 392), 256, 0, stream>>>(x, 0, nullptr, nullptr, qkv_w, qkv_b,
                                                 nullptr, 0, nullptr, qkv, 25088, 256, 768, 1.f);
    // 2. ref_qk = x_ref @ ref_qk_w + b
    mfma_gemm<<<dim3(8, 4), 256, 0, stream>>>(x_ref, 0, nullptr, nullptr, ref_qk_w, ref_qk_b,
                                              nullptr, 0, ref_qk, nullptr, 256, 256, 512, 1.f);
    // 3. ref_q_t / ref_v_t
    refprep_kernel<<<256, 256, 0, stream>>>(ref_qk, diff_mu, diff_ls, ref_q_t, ref_v_t);
    // 4. ref_attn scores
    refattn_kernel<<<4096, 256, 0, stream>>>(qkv, ref_q_t, ref_attn);
    // 5. 3x diffusion
    for (int it = 0; it < 3; ++it) {
        conv_kernel<<<392, 256, 0, stream>>>(ref_attn, conv_w, conv_b, u_buf);
        lnstats_kernel<<<64, 256, 0, stream>>>(u_buf, stats);
        lngelu_kernel<<<3136, 256, 0, stream>>>(u_buf, stats, ref_attn);
    }
    // 6. softmax @ ref_v + shortcut + LN -> ln_t
    qnew_pre_kernel<<<6272, 256, 0, stream>>>(qkv, ref_attn, ref_v_t,
                                              q_norm_w, q_norm_b, ln_t);
    // 7. q_new = (ln_t @ q_proj_w + b + qsc) * SCALE
    mfma_gemm<<<dim3(4, 392), 256, 0, stream>>>(ln_t, 1, nullptr, nullptr, q_proj_w, q_proj_b,
                                                qkv, 768, nullptr, q_new, 25088, 256, 256, SCALE_T);
    // 8. window attention (MFMA, 1 wave per (b,h))
    winattn_kernel<<<1024, 256, 0, stream>>>(qkv, q_new, rel_bias, attn_out);
    // 9. out0 = attn_out @ proj_w + b
    mfma_gemm<<<dim3(4, 392), 256, 0, stream>>>(attn_out, 1, nullptr, nullptr, proj_w, proj_b,
                                                nullptr, 0, out0, nullptr, 25088, 256, 256, 1.f);
    // 10/11. t_k, t_v
    mfma_gemm<<<dim3(6, 392), 256, 0, stream>>>(out0, 2, dth_tok, seg_tok, glob_k_w, glob_k_b,
                                                nullptr, 0, nullptr, t_k, 25088, 384, 384, 1.f);
    mfma_gemm<<<dim3(6, 392), 256, 0, stream>>>(out0, 2, dth_tok, seg_tok, glob_v_w, glob_v_b,
                                                nullptr, 0, nullptr, t_v, 25088, 384, 384, 1.f);
    // 12/13. depth_q, seg_q
    mfma_gemm<<<dim3(1, 392), 256, 0, stream>>>(dth_tok, 0, nullptr, nullptr, cls_dth_w, cls_dth_b,
                                                nullptr, 0, nullptr, depth_q, 25088, 64, 64, SCALE_T);
    mfma_gemm<<<dim3(1, 392), 256, 0, stream>>>(seg_tok, 0, nullptr, nullptr, cls_seg_w, cls_seg_b,
                                                nullptr, 0, nullptr, seg_q, 25088, 64, 64, SCALE_T);
    // 14. class-token attention (MFMA, 1 wave per (b,h))
    clsattn_kernel<<<1024, 256, 0, stream>>>(t_k, t_v, depth_q, seg_q, d_pre, s_pre);
    // 15/16. final proj_dth
    mfma_gemm<<<dim3(1, 392), 256, 0, stream>>>(d_pre, 1, nullptr, nullptr, proj_dth_w, proj_dth_b,
                                                nullptr, 0, out_d, nullptr, 25088, 64, 64, 1.f);
    mfma_gemm<<<dim3(1, 392), 256, 0, stream>>>(s_pre, 1, nullptr, nullptr, proj_dth_w, proj_dth_b,
                                                nullptr, 0, out_s, nullptr, 25088, 64, 64, 1.f);
}